// Round 3
// baseline (215.847 us; speedup 1.0000x reference)
//
#include <hip/hip_runtime.h>
#include <hip/hip_bf16.h>

#define NUM_HEADS 16
#define HEAD_DIM 64
#define DMODEL 1024
#define SEQ 2048
#define BATCH 2
#define MROWS (BATCH*SEQ)

typedef __bf16 bf16;
typedef __bf16 bf16x4 __attribute__((ext_vector_type(4)));
typedef __bf16 bf16x8 __attribute__((ext_vector_type(8)));
typedef float f32x4 __attribute__((ext_vector_type(4)));

#define MFMA16(a, b, c) __builtin_amdgcn_mfma_f32_16x16x32_bf16((a), (b), (c), 0, 0, 0)

// 0.125 * log2(e): folded into Q so QK^T logits land in exp2 domain
#define QSCALE 0.1803368801111444f

__device__ __forceinline__ void gld16(const void* g, void* l) {
    __builtin_amdgcn_global_load_lds(
        (const __attribute__((address_space(1))) void*)g,
        (__attribute__((address_space(3))) void*)l, 16, 0, 0);
}

// ---------------- conversion kernels ----------------

__global__ __launch_bounds__(256) void cvt_f32_bf16(const float* __restrict__ in,
                                                    bf16* __restrict__ out, int n4) {
    int i = blockIdx.x * 256 + threadIdx.x;
    if (i >= n4) return;
    float4 v = *(const float4*)(in + (size_t)i * 4);
    bf16x4 o = { (bf16)v.x, (bf16)v.y, (bf16)v.z, (bf16)v.w };
    *(bf16x4*)(out + (size_t)i * 4) = o;
}

// w [1024][1024] f32 -> wT bf16 [1024][1024], wT[n][k] = w[k][n]
__global__ __launch_bounds__(256) void cvt_trans(const float* __restrict__ w0, const float* __restrict__ w1,
                                                 const float* __restrict__ w2, const float* __restrict__ w3,
                                                 bf16* __restrict__ o0, bf16* __restrict__ o1,
                                                 bf16* __restrict__ o2, bf16* __restrict__ o3) {
    const float* w = blockIdx.z == 0 ? w0 : blockIdx.z == 1 ? w1 : blockIdx.z == 2 ? w2 : w3;
    bf16* o = blockIdx.z == 0 ? o0 : blockIdx.z == 1 ? o1 : blockIdx.z == 2 ? o2 : o3;
    __shared__ bf16 tile[64][65];
    int k0 = blockIdx.y * 64, n0 = blockIdx.x * 64;
    int tc = threadIdx.x & 63;
    int tr0 = threadIdx.x >> 6;
#pragma unroll
    for (int i = 0; i < 16; i++) {
        int r = tr0 + i * 4;  // k row
        tile[r][tc] = (bf16)w[(size_t)(k0 + r) * DMODEL + n0 + tc];
    }
    __syncthreads();
#pragma unroll
    for (int i = 0; i < 16; i++) {
        int r = tr0 + i * 4;  // n row of output
        o[(size_t)(n0 + r) * DMODEL + k0 + tc] = tile[tc][r];
    }
}

// ---------------- GEMM core: C[128][128] tile = A[m][k] * Bt[n][k]^T ----------------

#define BM 128
#define BN 128
#define BK 32

__device__ __forceinline__ void gemm_core(const bf16* __restrict__ A, const bf16* __restrict__ Bt,
                                          int m0, int n0, int Kdim,
                                          bf16* As, bf16* Bs, f32x4 acc[4][4]) {
    int t = threadIdx.x;
    int lane = t & 63;
    int wave = t >> 6;
    int wm = (wave >> 1) * 64;
    int wn = (wave & 1) * 64;
#pragma unroll
    for (int mf = 0; mf < 4; mf++)
#pragma unroll
        for (int nf = 0; nf < 4; nf++) acc[mf][nf] = (f32x4){0.f, 0.f, 0.f, 0.f};

    int arow = lane & 15, kg = lane >> 4;

    for (int k0 = 0; k0 < Kdim; k0 += BK) {
        __syncthreads();
#pragma unroll
        for (int it = 0; it < 2; it++) {
            int chunk = it * 256 + t;
            int rr = chunk >> 2, cc = chunk & 3;
            gld16(A + (size_t)(m0 + rr) * Kdim + k0 + cc * 8, As + chunk * 8);
            gld16(Bt + (size_t)(n0 + rr) * Kdim + k0 + cc * 8, Bs + chunk * 8);
        }
        __syncthreads();
        bf16x8 af[4], bfr[4];
#pragma unroll
        for (int mf = 0; mf < 4; mf++)
            af[mf] = *(const bf16x8*)(As + (wm + mf * 16 + arow) * BK + kg * 8);
#pragma unroll
        for (int nf = 0; nf < 4; nf++)
            bfr[nf] = *(const bf16x8*)(Bs + (wn + nf * 16 + arow) * BK + kg * 8);
#pragma unroll
        for (int mf = 0; mf < 4; mf++)
#pragma unroll
            for (int nf = 0; nf < 4; nf++)
                acc[mf][nf] = MFMA16(af[mf], bfr[nf], acc[mf][nf]);
    }
}

// z=0 -> Q head-major [B][H][S][D], pre-scaled by QSCALE; z=1 -> K head-major; z=2 -> V [B][H][D][S]
__global__ __launch_bounds__(256) void gemm_qkv(const bf16* __restrict__ xb,
                                                const bf16* __restrict__ wqT, const bf16* __restrict__ wkT,
                                                const bf16* __restrict__ wvT,
                                                bf16* __restrict__ Qh, bf16* __restrict__ Kh,
                                                bf16* __restrict__ Vt) {
    __shared__ __attribute__((aligned(16))) bf16 As[BM * BK];
    __shared__ __attribute__((aligned(16))) bf16 Bs[BN * BK];
    int z = blockIdx.z;
    const bf16* Bt = z == 0 ? wqT : z == 1 ? wkT : wvT;
    int m0 = blockIdx.y * BM, n0 = blockIdx.x * BN;
    f32x4 acc[4][4];
    gemm_core(xb, Bt, m0, n0, DMODEL, As, Bs, acc);

    int lane = threadIdx.x & 63, wave = threadIdx.x >> 6;
    int wm = (wave >> 1) * 64, wn = (wave & 1) * 64;
    int col0 = n0 + wn + (lane & 15);
    int row0 = m0 + wm + (lane >> 4) * 4;
    if (z < 2) {
        bf16* O = z == 0 ? Qh : Kh;
        float scl = z == 0 ? QSCALE : 1.0f;
#pragma unroll
        for (int mf = 0; mf < 4; mf++)
#pragma unroll
            for (int nf = 0; nf < 4; nf++) {
                int n = col0 + nf * 16;
                int mb = row0 + mf * 16;
                int hh = n >> 6, d = n & 63;
#pragma unroll
                for (int i2 = 0; i2 < 4; i2++) {
                    int m = mb + i2;
                    int bb = m >> 11, s = m & 2047;
                    O[(((size_t)bb * NUM_HEADS + hh) * SEQ + s) * HEAD_DIM + d] =
                        (bf16)(acc[mf][nf][i2] * scl);
                }
            }
    } else {
#pragma unroll
        for (int mf = 0; mf < 4; mf++)
#pragma unroll
            for (int nf = 0; nf < 4; nf++) {
                int n = col0 + nf * 16;
                int m = row0 + mf * 16;
                int b = m >> 11, s = m & 2047;
                int h = n >> 6, d = n & 63;
                bf16x4 pack = { (bf16)acc[mf][nf][0], (bf16)acc[mf][nf][1],
                                (bf16)acc[mf][nf][2], (bf16)acc[mf][nf][3] };
                *(bf16x4*)(Vt + ((size_t)(b * NUM_HEADS + h) * HEAD_DIM + d) * SEQ + s) = pack;
            }
    }
}

__global__ __launch_bounds__(256) void gemm_outp(const bf16* __restrict__ at,
                                                 const bf16* __restrict__ woT,
                                                 float* __restrict__ out) {
    __shared__ __attribute__((aligned(16))) bf16 As[BM * BK];
    __shared__ __attribute__((aligned(16))) bf16 Bs[BN * BK];
    int m0 = blockIdx.y * BM, n0 = blockIdx.x * BN;
    f32x4 acc[4][4];
    gemm_core(at, woT, m0, n0, DMODEL, As, Bs, acc);

    int lane = threadIdx.x & 63, wave = threadIdx.x >> 6;
    int wm = (wave >> 1) * 64, wn = (wave & 1) * 64;
    int col0 = n0 + wn + (lane & 15);
    int row0 = m0 + wm + (lane >> 4) * 4;
#pragma unroll
    for (int mf = 0; mf < 4; mf++)
#pragma unroll
        for (int nf = 0; nf < 4; nf++) {
            int n = col0 + nf * 16;
            int mb = row0 + mf * 16;
#pragma unroll
            for (int i2 = 0; i2 < 4; i2++)
                out[(size_t)(mb + i2) * DMODEL + n] = acc[mf][nf][i2];
        }
}

// ---------------- flash attention, swapped-QK^T, prefetched, balanced ----------------
// grid 2048 x 1, block 128 (2 waves). Per (b,h): 64 blocks; wave0 -> q-tile i,
// wave1 -> q-tile 127-i  => every block costs ~34 KV iterations (uniform).
// XCD remap: id&7 = xcd; each XCD owns 4 (b,h) -> K+V 2MB fits its 4MB L2.
// Register prefetch: V(kt) issued before QK mfmas, K(kt+1) issued right after
// (kf regs dead after mfma issue) — both covered by softmax + P-LDS phase.
__global__ __launch_bounds__(128, 4) void attn_kernel(const bf16* __restrict__ Qh, const bf16* __restrict__ Kh,
                                                      const bf16* __restrict__ Vt, bf16* __restrict__ attn) {
    __shared__ __attribute__((aligned(16))) bf16 Pl[2 * 16 * 64];
    int id = blockIdx.x;
    int xcd = id & 7, slot = id >> 3;        // slot 0..255
    int hb = xcd * 4 + (slot >> 6);          // 4 (b,h) per XCD
    int i0 = slot & 63;
    int b = hb >> 4, h = hb & 15;
    int t = threadIdx.x, lane = t & 63, wave = t >> 6;
    int l15 = lane & 15, lg = lane >> 4;
    int tile = wave ? (127 - i0) : i0;
    int q0 = tile * 16;
    int nkt = (tile >> 2) + 1;

    const bf16* Qb = Qh + ((size_t)(b * NUM_HEADS + h) * SEQ) * HEAD_DIM;
    const bf16* Kb = Kh + ((size_t)(b * NUM_HEADS + h) * SEQ) * HEAD_DIM;
    const bf16* Vb = Vt + ((size_t)(b * NUM_HEADS + h) * HEAD_DIM) * SEQ;  // [D][S]

    // Q fragment for q rows q0..q0+15 (pre-scaled by QSCALE in GEMM epilogue)
    bf16x8 qf[2];
#pragma unroll
    for (int ks = 0; ks < 2; ks++)
        qf[ks] = *(const bf16x8*)(Qb + (size_t)(q0 + l15) * HEAD_DIM + ks * 32 + lg * 8);

    f32x4 oacc[4];
#pragma unroll
    for (int df = 0; df < 4; df++) oacc[df] = (f32x4){0.f, 0.f, 0.f, 0.f};
    float mrun = -1e30f, lrun = 0.f;

    char* Pw = (char*)Pl + wave * 2048;
    int swz = (l15 & 7) << 4;

    // prologue: K fragments for kt=0
    bf16x8 kf[4][2];
#pragma unroll
    for (int cf = 0; cf < 4; cf++)
#pragma unroll
        for (int ks = 0; ks < 2; ks++)
            kf[cf][ks] = *(const bf16x8*)(Kb + (size_t)(cf * 16 + l15) * HEAD_DIM + ks * 32 + lg * 8);

    for (int kt = 0; kt < nkt; kt++) {
        int kv0 = kt * 64;
        // prefetch V(kt) — consumed at PV below, latency covered by QK+softmax
        bf16x8 vf[2][4];
#pragma unroll
        for (int ks = 0; ks < 2; ks++)
#pragma unroll
            for (int df = 0; df < 4; df++)
                vf[ks][df] = *(const bf16x8*)(Vb + (size_t)(df * 16 + l15) * SEQ + kv0 + ks * 32 + lg * 8);

        // QK^T (swapped): st[cf][i] = S[q=q0+l15][kv = kv0 + cf*16 + lg*4 + i]
        f32x4 st[4];
        __builtin_amdgcn_s_setprio(1);
#pragma unroll
        for (int cf = 0; cf < 4; cf++) {
            st[cf] = (f32x4){0.f, 0.f, 0.f, 0.f};
#pragma unroll
            for (int ks = 0; ks < 2; ks++)
                st[cf] = MFMA16(kf[cf][ks], qf[ks], st[cf]);
        }
        __builtin_amdgcn_s_setprio(0);

        // prefetch K(kt+1) into kf (dead after mfma issue); clamp on last iter
        int kvn = (kt + 1 < nkt ? kt + 1 : kt) * 64;
#pragma unroll
        for (int cf = 0; cf < 4; cf++)
#pragma unroll
            for (int ks = 0; ks < 2; ks++)
                kf[cf][ks] = *(const bf16x8*)(Kb + (size_t)(kvn + cf * 16 + l15) * HEAD_DIM + ks * 32 + lg * 8);

        // causal mask: only the final tile can have kv > q
        if (kt == nkt - 1) {
            int qrow = q0 + l15;
#pragma unroll
            for (int cf = 0; cf < 4; cf++)
#pragma unroll
                for (int i = 0; i < 4; i++) {
                    int kv = kv0 + cf * 16 + lg * 4 + i;
                    if (kv > qrow) st[cf][i] = -1e30f;
                }
        }

        // softmax with defer-max (T13): skip O-rescale when max didn't grow much
        float mx = -1e30f;
#pragma unroll
        for (int cf = 0; cf < 4; cf++)
#pragma unroll
            for (int i = 0; i < 4; i++) mx = fmaxf(mx, st[cf][i]);
        mx = fmaxf(mx, __shfl_xor(mx, 16, 64));
        mx = fmaxf(mx, __shfl_xor(mx, 32, 64));
        if (!__all(mx <= mrun + 8.0f)) {
            float mnew = fmaxf(mrun, mx);
            float alpha = exp2f(mrun - mnew);
            float av[4];
#pragma unroll
            for (int i = 0; i < 4; i++) av[i] = __shfl(alpha, lg * 4 + i, 64);
#pragma unroll
            for (int df = 0; df < 4; df++)
#pragma unroll
                for (int i = 0; i < 4; i++) oacc[df][i] *= av[i];
            lrun *= alpha;
            mrun = mnew;
        }
        float ps = 0.f;
        bf16x4 pb[4];
#pragma unroll
        for (int cf = 0; cf < 4; cf++)
#pragma unroll
            for (int i = 0; i < 4; i++) {
                float p = exp2f(st[cf][i] - mrun);
                ps += p;
                pb[cf][i] = (bf16)p;
            }
        ps += __shfl_xor(ps, 16, 64);
        ps += __shfl_xor(ps, 32, 64);
        lrun += ps;

        // P -> LDS (XOR-swizzled rows), read back as PV A-fragment
#pragma unroll
        for (int cf = 0; cf < 4; cf++) {
            int off = (l15 * 128 + cf * 32 + lg * 8) ^ swz;
            *(bf16x4*)(Pw + off) = pb[cf];
        }
        asm volatile("s_waitcnt lgkmcnt(0)" ::: "memory");
        __builtin_amdgcn_sched_barrier(0);
        bf16x8 pa[2];
#pragma unroll
        for (int ks = 0; ks < 2; ks++) {
            int off = (l15 * 128 + ks * 64 + lg * 16) ^ swz;
            pa[ks] = *(const bf16x8*)(Pw + off);
        }
        __builtin_amdgcn_s_setprio(1);
#pragma unroll
        for (int ks = 0; ks < 2; ks++)
#pragma unroll
            for (int df = 0; df < 4; df++)
                oacc[df] = MFMA16(pa[ks], vf[ks][df], oacc[df]);
        __builtin_amdgcn_s_setprio(0);
    }
    // final: divide row q by lrun[q]; stats live at lane q (q<16)
    float lrec = 1.0f / lrun;
    float lv[4];
#pragma unroll
    for (int i = 0; i < 4; i++) lv[i] = __shfl(lrec, lg * 4 + i, 64);
#pragma unroll
    for (int df = 0; df < 4; df++)
#pragma unroll
        for (int i = 0; i < 4; i++) {
            int qrow = q0 + lg * 4 + i;
            int d = df * 16 + l15;
            attn[((size_t)(b * SEQ + qrow)) * DMODEL + h * HEAD_DIM + d] = (bf16)(oacc[df][i] * lv[i]);
        }
}

// ---------------- launch ----------------

extern "C" void kernel_launch(void* const* d_in, const int* in_sizes, int n_in,
                              void* d_out, int out_size, void* d_ws, size_t ws_size,
                              hipStream_t stream) {
    const float* x  = (const float*)d_in[0];
    const float* wq = (const float*)d_in[1];
    const float* wk = (const float*)d_in[2];
    const float* wv = (const float*)d_in[3];
    const float* wo = (const float*)d_in[4];
    float* out = (float*)d_out;

    char* w = (char*)d_ws;
    bf16* xb  = (bf16*)(w);                        // 8 MB
    bf16* wqT = (bf16*)(w + (8ull  << 20));        // 2 MB
    bf16* wkT = (bf16*)(w + (10ull << 20));
    bf16* wvT = (bf16*)(w + (12ull << 20));
    bf16* woT = (bf16*)(w + (14ull << 20));
    bf16* Qh  = (bf16*)(w + (16ull << 20));        // 8 MB, [B][H][S][D]
    bf16* Kh  = (bf16*)(w + (24ull << 20));        // 8 MB, [B][H][S][D]
    bf16* Vt  = (bf16*)(w + (32ull << 20));        // 8 MB, [B][H][D][S]
    bf16* at  = (bf16*)(w + (40ull << 20));        // 8 MB  (total 48 MB)

    cvt_f32_bf16<<<(MROWS * DMODEL / 4 + 255) / 256, 256, 0, stream>>>(x, xb, MROWS * DMODEL / 4);
    cvt_trans<<<dim3(16, 16, 4), 256, 0, stream>>>(wq, wk, wv, wo, wqT, wkT, wvT, woT);
    gemm_qkv<<<dim3(DMODEL / BN, MROWS / BM, 3), 256, 0, stream>>>(xb, wqT, wkT, wvT, Qh, Kh, Vt);
    attn_kernel<<<dim3(2048, 1, 1), 128, 0, stream>>>(Qh, Kh, Vt, at);
    gemm_outp<<<dim3(DMODEL / BN, MROWS / BM), 256, 0, stream>>>(at, woT, out);
}

// Round 4
// 189.575 us; speedup vs baseline: 1.1386x; 1.1386x over previous
//
#include <hip/hip_runtime.h>
#include <hip/hip_bf16.h>

#define NUM_HEADS 16
#define HEAD_DIM 64
#define DMODEL 1024
#define SEQ 2048
#define BATCH 2
#define MROWS (BATCH*SEQ)

typedef __bf16 bf16;
typedef __bf16 bf16x4 __attribute__((ext_vector_type(4)));
typedef __bf16 bf16x8 __attribute__((ext_vector_type(8)));
typedef float f32x4 __attribute__((ext_vector_type(4)));

#define MFMA16(a, b, c) __builtin_amdgcn_mfma_f32_16x16x32_bf16((a), (b), (c), 0, 0, 0)

// 0.125 * log2(e): folded into Q so QK^T logits land in exp2 domain
#define QSCALE 0.1803368801111444f

__device__ __forceinline__ float fast_exp2(float x) {
    float r;
    asm("v_exp_f32 %0, %1" : "=v"(r) : "v"(x));
    return r;
}

__device__ __forceinline__ void gld16(const void* g, void* l) {
    __builtin_amdgcn_global_load_lds(
        (const __attribute__((address_space(1))) void*)g,
        (__attribute__((address_space(3))) void*)l, 16, 0, 0);
}

// ---------------- conversion kernels ----------------

__global__ __launch_bounds__(256) void cvt_f32_bf16(const float* __restrict__ in,
                                                    bf16* __restrict__ out, int n4) {
    int i = blockIdx.x * 256 + threadIdx.x;
    if (i >= n4) return;
    float4 v = *(const float4*)(in + (size_t)i * 4);
    bf16x4 o = { (bf16)v.x, (bf16)v.y, (bf16)v.z, (bf16)v.w };
    *(bf16x4*)(out + (size_t)i * 4) = o;
}

// w [1024][1024] f32 -> wT bf16 [1024][1024], wT[n][k] = w[k][n]
__global__ __launch_bounds__(256) void cvt_trans(const float* __restrict__ w0, const float* __restrict__ w1,
                                                 const float* __restrict__ w2, const float* __restrict__ w3,
                                                 bf16* __restrict__ o0, bf16* __restrict__ o1,
                                                 bf16* __restrict__ o2, bf16* __restrict__ o3) {
    const float* w = blockIdx.z == 0 ? w0 : blockIdx.z == 1 ? w1 : blockIdx.z == 2 ? w2 : w3;
    bf16* o = blockIdx.z == 0 ? o0 : blockIdx.z == 1 ? o1 : blockIdx.z == 2 ? o2 : o3;
    __shared__ bf16 tile[64][65];
    int k0 = blockIdx.y * 64, n0 = blockIdx.x * 64;
    int tc = threadIdx.x & 63;
    int tr0 = threadIdx.x >> 6;
#pragma unroll
    for (int i = 0; i < 16; i++) {
        int r = tr0 + i * 4;  // k row
        tile[r][tc] = (bf16)w[(size_t)(k0 + r) * DMODEL + n0 + tc];
    }
    __syncthreads();
#pragma unroll
    for (int i = 0; i < 16; i++) {
        int r = tr0 + i * 4;  // n row of output
        o[(size_t)(n0 + r) * DMODEL + k0 + tc] = tile[tc][r];
    }
}

// ---------------- GEMM core: C[128][128] tile = A[m][k] * Bt[n][k]^T ----------------

#define BM 128
#define BN 128
#define BK 32

__device__ __forceinline__ void gemm_core(const bf16* __restrict__ A, const bf16* __restrict__ Bt,
                                          int m0, int n0, int Kdim,
                                          bf16* As, bf16* Bs, f32x4 acc[4][4]) {
    int t = threadIdx.x;
    int lane = t & 63;
    int wave = t >> 6;
    int wm = (wave >> 1) * 64;
    int wn = (wave & 1) * 64;
#pragma unroll
    for (int mf = 0; mf < 4; mf++)
#pragma unroll
        for (int nf = 0; nf < 4; nf++) acc[mf][nf] = (f32x4){0.f, 0.f, 0.f, 0.f};

    int arow = lane & 15, kg = lane >> 4;

    for (int k0 = 0; k0 < Kdim; k0 += BK) {
        __syncthreads();
#pragma unroll
        for (int it = 0; it < 2; it++) {
            int chunk = it * 256 + t;
            int rr = chunk >> 2, cc = chunk & 3;
            gld16(A + (size_t)(m0 + rr) * Kdim + k0 + cc * 8, As + chunk * 8);
            gld16(Bt + (size_t)(n0 + rr) * Kdim + k0 + cc * 8, Bs + chunk * 8);
        }
        __syncthreads();
        bf16x8 af[4], bfr[4];
#pragma unroll
        for (int mf = 0; mf < 4; mf++)
            af[mf] = *(const bf16x8*)(As + (wm + mf * 16 + arow) * BK + kg * 8);
#pragma unroll
        for (int nf = 0; nf < 4; nf++)
            bfr[nf] = *(const bf16x8*)(Bs + (wn + nf * 16 + arow) * BK + kg * 8);
#pragma unroll
        for (int mf = 0; mf < 4; mf++)
#pragma unroll
            for (int nf = 0; nf < 4; nf++)
                acc[mf][nf] = MFMA16(af[mf], bfr[nf], acc[mf][nf]);
    }
}

// z=0 -> Q head-major [B][H][S][D], pre-scaled by QSCALE; z=1 -> K head-major; z=2 -> V [B][H][D][S]
__global__ __launch_bounds__(256) void gemm_qkv(const bf16* __restrict__ xb,
                                                const bf16* __restrict__ wqT, const bf16* __restrict__ wkT,
                                                const bf16* __restrict__ wvT,
                                                bf16* __restrict__ Qh, bf16* __restrict__ Kh,
                                                bf16* __restrict__ Vt) {
    __shared__ __attribute__((aligned(16))) bf16 As[BM * BK];
    __shared__ __attribute__((aligned(16))) bf16 Bs[BN * BK];
    int z = blockIdx.z;
    const bf16* Bt = z == 0 ? wqT : z == 1 ? wkT : wvT;
    int m0 = blockIdx.y * BM, n0 = blockIdx.x * BN;
    f32x4 acc[4][4];
    gemm_core(xb, Bt, m0, n0, DMODEL, As, Bs, acc);

    int lane = threadIdx.x & 63, wave = threadIdx.x >> 6;
    int wm = (wave >> 1) * 64, wn = (wave & 1) * 64;
    int col0 = n0 + wn + (lane & 15);
    int row0 = m0 + wm + (lane >> 4) * 4;
    if (z < 2) {
        bf16* O = z == 0 ? Qh : Kh;
        float scl = z == 0 ? QSCALE : 1.0f;
#pragma unroll
        for (int mf = 0; mf < 4; mf++)
#pragma unroll
            for (int nf = 0; nf < 4; nf++) {
                int n = col0 + nf * 16;
                int mb = row0 + mf * 16;
                int hh = n >> 6, d = n & 63;
#pragma unroll
                for (int i2 = 0; i2 < 4; i2++) {
                    int m = mb + i2;
                    int bb = m >> 11, s = m & 2047;
                    O[(((size_t)bb * NUM_HEADS + hh) * SEQ + s) * HEAD_DIM + d] =
                        (bf16)(acc[mf][nf][i2] * scl);
                }
            }
    } else {
#pragma unroll
        for (int mf = 0; mf < 4; mf++)
#pragma unroll
            for (int nf = 0; nf < 4; nf++) {
                int n = col0 + nf * 16;
                int m = row0 + mf * 16;
                int b = m >> 11, s = m & 2047;
                int h = n >> 6, d = n & 63;
                bf16x4 pack = { (bf16)acc[mf][nf][0], (bf16)acc[mf][nf][1],
                                (bf16)acc[mf][nf][2], (bf16)acc[mf][nf][3] };
                *(bf16x4*)(Vt + ((size_t)(b * NUM_HEADS + h) * HEAD_DIM + d) * SEQ + s) = pack;
            }
    }
}

__global__ __launch_bounds__(256) void gemm_outp(const bf16* __restrict__ at,
                                                 const bf16* __restrict__ woT,
                                                 float* __restrict__ out) {
    __shared__ __attribute__((aligned(16))) bf16 As[BM * BK];
    __shared__ __attribute__((aligned(16))) bf16 Bs[BN * BK];
    int m0 = blockIdx.y * BM, n0 = blockIdx.x * BN;
    f32x4 acc[4][4];
    gemm_core(at, woT, m0, n0, DMODEL, As, Bs, acc);

    int lane = threadIdx.x & 63, wave = threadIdx.x >> 6;
    int wm = (wave >> 1) * 64, wn = (wave & 1) * 64;
    int col0 = n0 + wn + (lane & 15);
    int row0 = m0 + wm + (lane >> 4) * 4;
#pragma unroll
    for (int mf = 0; mf < 4; mf++)
#pragma unroll
        for (int nf = 0; nf < 4; nf++) {
            int n = col0 + nf * 16;
            int mb = row0 + mf * 16;
#pragma unroll
            for (int i2 = 0; i2 < 4; i2++)
                out[(size_t)(mb + i2) * DMODEL + n] = acc[mf][nf][i2];
        }
}

// ---------------- flash attention, swapped-QK^T, 32 q-rows/wave ----------------
// grid 1024, block 128 (2 independent waves, no barriers). Each wave owns 32
// q-rows as TWO 16-row fragments sharing every K/V fragment load (2x arith
// intensity). Pairing: wave0 -> 32-row tile i0, wave1 -> tile 63-i0 (uniform
// block cost). XCD remap: id&7 = xcd; 4 (b,h) per XCD -> K+V 2MB fits its L2.
// NO inline-asm memory barriers in the loop: P round-trip is plain C++ LDS,
// so the compiler inserts precise lgkmcnt waits and is free to hoist V loads
// and software-pipeline K loads across iterations.
__global__ __launch_bounds__(128) void attn_kernel(const bf16* __restrict__ Qh, const bf16* __restrict__ Kh,
                                                   const bf16* __restrict__ Vt, bf16* __restrict__ attn) {
    __shared__ __attribute__((aligned(16))) bf16 Pl[2 * 2 * 16 * 64];  // 2 waves x 2 frags x 2KB
    int id = blockIdx.x;
    int xcd = id & 7, slot = id >> 3;        // slot 0..127
    int hb = xcd * 4 + (slot >> 5);          // 4 (b,h) per XCD
    int i0 = slot & 31;
    int b = hb >> 4, h = hb & 15;
    int t = threadIdx.x, lane = t & 63, wave = t >> 6;
    int l15 = lane & 15, lg = lane >> 4;
    int tile = wave ? (63 - i0) : i0;        // 32-row q tile, 0..63
    int q0 = tile * 32;
    int nkt = (tile >> 1) + 1;               // KV tiles of 64 needed

    const bf16* Qb = Qh + ((size_t)(b * NUM_HEADS + h) * SEQ) * HEAD_DIM;
    const bf16* Kb = Kh + ((size_t)(b * NUM_HEADS + h) * SEQ) * HEAD_DIM;
    const bf16* Vb = Vt + ((size_t)(b * NUM_HEADS + h) * HEAD_DIM) * SEQ;  // [D][S]

    // Q fragments: frag f covers q rows q0+f*16 .. +15 (pre-scaled by QSCALE)
    bf16x8 qf[2][2];
#pragma unroll
    for (int f = 0; f < 2; f++)
#pragma unroll
        for (int ks = 0; ks < 2; ks++)
            qf[f][ks] = *(const bf16x8*)(Qb + (size_t)(q0 + f * 16 + l15) * HEAD_DIM + ks * 32 + lg * 8);

    f32x4 oacc[2][4];
#pragma unroll
    for (int f = 0; f < 2; f++)
#pragma unroll
        for (int df = 0; df < 4; df++) oacc[f][df] = (f32x4){0.f, 0.f, 0.f, 0.f};
    float mrun[2] = {-1e30f, -1e30f}, lrun[2] = {0.f, 0.f};

    char* Pw = (char*)Pl + wave * 4096;
    int swz = (l15 & 7) << 4;

    for (int kt = 0; kt < nkt; kt++) {
        int kv0 = kt * 64;
        // QK^T (swapped): st[f][cf][i] = S[q=q0+f*16+l15][kv = kv0+cf*16+lg*4+i]
        f32x4 st[2][4];
#pragma unroll
        for (int cf = 0; cf < 4; cf++) {
            bf16x8 kfr[2];
#pragma unroll
            for (int ks = 0; ks < 2; ks++)
                kfr[ks] = *(const bf16x8*)(Kb + (size_t)(kv0 + cf * 16 + l15) * HEAD_DIM + ks * 32 + lg * 8);
            st[0][cf] = (f32x4){0.f, 0.f, 0.f, 0.f};
            st[1][cf] = (f32x4){0.f, 0.f, 0.f, 0.f};
            __builtin_amdgcn_s_setprio(1);
#pragma unroll
            for (int ks = 0; ks < 2; ks++) {
                st[0][cf] = MFMA16(kfr[ks], qf[0][ks], st[0][cf]);
                st[1][cf] = MFMA16(kfr[ks], qf[1][ks], st[1][cf]);
            }
            __builtin_amdgcn_s_setprio(0);
        }
        // causal mask: only the final tile can have kv > q
        if (kt == nkt - 1) {
#pragma unroll
            for (int f = 0; f < 2; f++) {
                int qrow = q0 + f * 16 + l15;
#pragma unroll
                for (int cf = 0; cf < 4; cf++)
#pragma unroll
                    for (int i = 0; i < 4; i++) {
                        int kv = kv0 + cf * 16 + lg * 4 + i;
                        if (kv > qrow) st[f][cf][i] = -1e30f;
                    }
            }
        }
        // softmax per fragment (tree reductions; defer-max T13)
#pragma unroll
        for (int f = 0; f < 2; f++) {
            float m01 = fmaxf(fmaxf(st[f][0][0], st[f][0][1]), fmaxf(st[f][0][2], st[f][0][3]));
            float m23 = fmaxf(fmaxf(st[f][1][0], st[f][1][1]), fmaxf(st[f][1][2], st[f][1][3]));
            float m45 = fmaxf(fmaxf(st[f][2][0], st[f][2][1]), fmaxf(st[f][2][2], st[f][2][3]));
            float m67 = fmaxf(fmaxf(st[f][3][0], st[f][3][1]), fmaxf(st[f][3][2], st[f][3][3]));
            float mx = fmaxf(fmaxf(m01, m23), fmaxf(m45, m67));
            mx = fmaxf(mx, __shfl_xor(mx, 16, 64));
            mx = fmaxf(mx, __shfl_xor(mx, 32, 64));
            if (!__all(mx <= mrun[f] + 8.0f)) {
                float mnew = fmaxf(mrun[f], mx);
                float alpha = fast_exp2(mrun[f] - mnew);
                float av[4];
#pragma unroll
                for (int i = 0; i < 4; i++) av[i] = __shfl(alpha, lg * 4 + i, 64);
#pragma unroll
                for (int df = 0; df < 4; df++)
#pragma unroll
                    for (int i = 0; i < 4; i++) oacc[f][df][i] *= av[i];
                lrun[f] *= alpha;
                mrun[f] = mnew;
            }
            float psc[4];
            bf16x4 pb[4];
#pragma unroll
            for (int cf = 0; cf < 4; cf++) {
                float p0 = fast_exp2(st[f][cf][0] - mrun[f]);
                float p1 = fast_exp2(st[f][cf][1] - mrun[f]);
                float p2 = fast_exp2(st[f][cf][2] - mrun[f]);
                float p3 = fast_exp2(st[f][cf][3] - mrun[f]);
                psc[cf] = (p0 + p1) + (p2 + p3);
                pb[cf][0] = (bf16)p0; pb[cf][1] = (bf16)p1;
                pb[cf][2] = (bf16)p2; pb[cf][3] = (bf16)p3;
            }
            float ps = (psc[0] + psc[1]) + (psc[2] + psc[3]);
            ps += __shfl_xor(ps, 16, 64);
            ps += __shfl_xor(ps, 32, 64);
            lrun[f] += ps;
            // P -> LDS (XOR-swizzled rows); plain C++ so compiler tracks deps
#pragma unroll
            for (int cf = 0; cf < 4; cf++) {
                int off = (l15 * 128 + cf * 32 + lg * 8) ^ swz;
                *(bf16x4*)(Pw + f * 2048 + off) = pb[cf];
            }
        }
        // read P back as PV A-fragments (compiler inserts precise lgkmcnt)
        bf16x8 pa[2][2];
#pragma unroll
        for (int f = 0; f < 2; f++)
#pragma unroll
            for (int ks = 0; ks < 2; ks++) {
                int off = (l15 * 128 + ks * 64 + lg * 16) ^ swz;
                pa[f][ks] = *(const bf16x8*)(Pw + f * 2048 + off);
            }
        // PV: both fragments share each V load
#pragma unroll
        for (int ks = 0; ks < 2; ks++)
#pragma unroll
            for (int df = 0; df < 4; df++) {
                bf16x8 bv = *(const bf16x8*)(Vb + (size_t)(df * 16 + l15) * SEQ + kv0 + ks * 32 + lg * 8);
                __builtin_amdgcn_s_setprio(1);
                oacc[0][df] = MFMA16(pa[0][ks], bv, oacc[0][df]);
                oacc[1][df] = MFMA16(pa[1][ks], bv, oacc[1][df]);
                __builtin_amdgcn_s_setprio(0);
            }
    }
    // epilogue: divide row q by lrun[q]; stats live at lane q (q<16)
#pragma unroll
    for (int f = 0; f < 2; f++) {
        float lrec = 1.0f / lrun[f];
        float lv[4];
#pragma unroll
        for (int i = 0; i < 4; i++) lv[i] = __shfl(lrec, lg * 4 + i, 64);
#pragma unroll
        for (int df = 0; df < 4; df++)
#pragma unroll
            for (int i = 0; i < 4; i++) {
                int qrow = q0 + f * 16 + lg * 4 + i;
                int d = df * 16 + l15;
                attn[((size_t)(b * SEQ + qrow)) * DMODEL + h * HEAD_DIM + d] = (bf16)(oacc[f][df][i] * lv[i]);
            }
    }
}

// ---------------- launch ----------------

extern "C" void kernel_launch(void* const* d_in, const int* in_sizes, int n_in,
                              void* d_out, int out_size, void* d_ws, size_t ws_size,
                              hipStream_t stream) {
    const float* x  = (const float*)d_in[0];
    const float* wq = (const float*)d_in[1];
    const float* wk = (const float*)d_in[2];
    const float* wv = (const float*)d_in[3];
    const float* wo = (const float*)d_in[4];
    float* out = (float*)d_out;

    char* w = (char*)d_ws;
    bf16* xb  = (bf16*)(w);                        // 8 MB
    bf16* wqT = (bf16*)(w + (8ull  << 20));        // 2 MB
    bf16* wkT = (bf16*)(w + (10ull << 20));
    bf16* wvT = (bf16*)(w + (12ull << 20));
    bf16* woT = (bf16*)(w + (14ull << 20));
    bf16* Qh  = (bf16*)(w + (16ull << 20));        // 8 MB, [B][H][S][D]
    bf16* Kh  = (bf16*)(w + (24ull << 20));        // 8 MB, [B][H][S][D]
    bf16* Vt  = (bf16*)(w + (32ull << 20));        // 8 MB, [B][H][D][S]
    bf16* at  = (bf16*)(w + (40ull << 20));        // 8 MB  (total 48 MB)

    cvt_f32_bf16<<<(MROWS * DMODEL / 4 + 255) / 256, 256, 0, stream>>>(x, xb, MROWS * DMODEL / 4);
    cvt_trans<<<dim3(16, 16, 4), 256, 0, stream>>>(wq, wk, wv, wo, wqT, wkT, wvT, woT);
    gemm_qkv<<<dim3(DMODEL / BN, MROWS / BM, 3), 256, 0, stream>>>(xb, wqT, wkT, wvT, Qh, Kh, Vt);
    attn_kernel<<<dim3(1024, 1, 1), 128, 0, stream>>>(Qh, Kh, Vt, at);
    gemm_outp<<<dim3(DMODEL / BN, MROWS / BM), 256, 0, stream>>>(at, woT, out);
}

// Round 5
// 176.757 us; speedup vs baseline: 1.2211x; 1.0725x over previous
//
#include <hip/hip_runtime.h>
#include <hip/hip_bf16.h>

#define NUM_HEADS 16
#define HEAD_DIM 64
#define DMODEL 1024
#define SEQ 2048
#define BATCH 2
#define MROWS (BATCH*SEQ)

typedef __bf16 bf16;
typedef __bf16 bf16x4 __attribute__((ext_vector_type(4)));
typedef __bf16 bf16x8 __attribute__((ext_vector_type(8)));
typedef float f32x4 __attribute__((ext_vector_type(4)));

#define MFMA16(a, b, c) __builtin_amdgcn_mfma_f32_16x16x32_bf16((a), (b), (c), 0, 0, 0)

// 0.125 * log2(e): folded into Q so QK^T logits land in exp2 domain
#define QSCALE 0.1803368801111444f

__device__ __forceinline__ float fast_exp2(float x) {
    float r;
    asm("v_exp_f32 %0, %1" : "=v"(r) : "v"(x));
    return r;
}

__device__ __forceinline__ void gld16(const void* g, void* l) {
    __builtin_amdgcn_global_load_lds(
        (const __attribute__((address_space(1))) void*)g,
        (__attribute__((address_space(3))) void*)l, 16, 0, 0);
}

// ---------------- conversion kernels ----------------

__global__ __launch_bounds__(256) void cvt_f32_bf16(const float* __restrict__ in,
                                                    bf16* __restrict__ out, int n4) {
    int i = blockIdx.x * 256 + threadIdx.x;
    if (i >= n4) return;
    float4 v = *(const float4*)(in + (size_t)i * 4);
    bf16x4 o = { (bf16)v.x, (bf16)v.y, (bf16)v.z, (bf16)v.w };
    *(bf16x4*)(out + (size_t)i * 4) = o;
}

// w [1024][1024] f32 -> wT bf16 [1024][1024], wT[n][k] = w[k][n]
__global__ __launch_bounds__(256) void cvt_trans(const float* __restrict__ w0, const float* __restrict__ w1,
                                                 const float* __restrict__ w2, const float* __restrict__ w3,
                                                 bf16* __restrict__ o0, bf16* __restrict__ o1,
                                                 bf16* __restrict__ o2, bf16* __restrict__ o3) {
    const float* w = blockIdx.z == 0 ? w0 : blockIdx.z == 1 ? w1 : blockIdx.z == 2 ? w2 : w3;
    bf16* o = blockIdx.z == 0 ? o0 : blockIdx.z == 1 ? o1 : blockIdx.z == 2 ? o2 : o3;
    __shared__ bf16 tile[64][65];
    int k0 = blockIdx.y * 64, n0 = blockIdx.x * 64;
    int tc = threadIdx.x & 63;
    int tr0 = threadIdx.x >> 6;
#pragma unroll
    for (int i = 0; i < 16; i++) {
        int r = tr0 + i * 4;  // k row
        tile[r][tc] = (bf16)w[(size_t)(k0 + r) * DMODEL + n0 + tc];
    }
    __syncthreads();
#pragma unroll
    for (int i = 0; i < 16; i++) {
        int r = tr0 + i * 4;  // n row of output
        o[(size_t)(n0 + r) * DMODEL + k0 + tc] = tile[tc][r];
    }
}

// ---------------- GEMM core: C[128][128] tile = A[m][k] * Bt[n][k]^T ----------------

#define BM 128
#define BN 128
#define BK 32

__device__ __forceinline__ void gemm_core(const bf16* __restrict__ A, const bf16* __restrict__ Bt,
                                          int m0, int n0, int Kdim,
                                          bf16* As, bf16* Bs, f32x4 acc[4][4]) {
    int t = threadIdx.x;
    int lane = t & 63;
    int wave = t >> 6;
    int wm = (wave >> 1) * 64;
    int wn = (wave & 1) * 64;
#pragma unroll
    for (int mf = 0; mf < 4; mf++)
#pragma unroll
        for (int nf = 0; nf < 4; nf++) acc[mf][nf] = (f32x4){0.f, 0.f, 0.f, 0.f};

    int arow = lane & 15, kg = lane >> 4;

    for (int k0 = 0; k0 < Kdim; k0 += BK) {
        __syncthreads();
#pragma unroll
        for (int it = 0; it < 2; it++) {
            int chunk = it * 256 + t;
            int rr = chunk >> 2, cc = chunk & 3;
            gld16(A + (size_t)(m0 + rr) * Kdim + k0 + cc * 8, As + chunk * 8);
            gld16(Bt + (size_t)(n0 + rr) * Kdim + k0 + cc * 8, Bs + chunk * 8);
        }
        __syncthreads();
        bf16x8 af[4], bfr[4];
#pragma unroll
        for (int mf = 0; mf < 4; mf++)
            af[mf] = *(const bf16x8*)(As + (wm + mf * 16 + arow) * BK + kg * 8);
#pragma unroll
        for (int nf = 0; nf < 4; nf++)
            bfr[nf] = *(const bf16x8*)(Bs + (wn + nf * 16 + arow) * BK + kg * 8);
#pragma unroll
        for (int mf = 0; mf < 4; mf++)
#pragma unroll
            for (int nf = 0; nf < 4; nf++)
                acc[mf][nf] = MFMA16(af[mf], bfr[nf], acc[mf][nf]);
    }
}

// z=0 -> Q head-major [B][H][S][D], pre-scaled by QSCALE; z=1 -> K head-major; z=2 -> V [B][H][D][S]
__global__ __launch_bounds__(256) void gemm_qkv(const bf16* __restrict__ xb,
                                                const bf16* __restrict__ wqT, const bf16* __restrict__ wkT,
                                                const bf16* __restrict__ wvT,
                                                bf16* __restrict__ Qh, bf16* __restrict__ Kh,
                                                bf16* __restrict__ Vt) {
    __shared__ __attribute__((aligned(16))) bf16 As[BM * BK];
    __shared__ __attribute__((aligned(16))) bf16 Bs[BN * BK];
    int z = blockIdx.z;
    const bf16* Bt = z == 0 ? wqT : z == 1 ? wkT : wvT;
    int m0 = blockIdx.y * BM, n0 = blockIdx.x * BN;
    f32x4 acc[4][4];
    gemm_core(xb, Bt, m0, n0, DMODEL, As, Bs, acc);

    int lane = threadIdx.x & 63, wave = threadIdx.x >> 6;
    int wm = (wave >> 1) * 64, wn = (wave & 1) * 64;
    int col0 = n0 + wn + (lane & 15);
    int row0 = m0 + wm + (lane >> 4) * 4;
    if (z < 2) {
        bf16* O = z == 0 ? Qh : Kh;
        float scl = z == 0 ? QSCALE : 1.0f;
#pragma unroll
        for (int mf = 0; mf < 4; mf++)
#pragma unroll
            for (int nf = 0; nf < 4; nf++) {
                int n = col0 + nf * 16;
                int mb = row0 + mf * 16;
                int hh = n >> 6, d = n & 63;
#pragma unroll
                for (int i2 = 0; i2 < 4; i2++) {
                    int m = mb + i2;
                    int bb = m >> 11, s = m & 2047;
                    O[(((size_t)bb * NUM_HEADS + hh) * SEQ + s) * HEAD_DIM + d] =
                        (bf16)(acc[mf][nf][i2] * scl);
                }
            }
    } else {
#pragma unroll
        for (int mf = 0; mf < 4; mf++)
#pragma unroll
            for (int nf = 0; nf < 4; nf++) {
                int n = col0 + nf * 16;
                int m = row0 + mf * 16;
                int b = m >> 11, s = m & 2047;
                int h = n >> 6, d = n & 63;
                bf16x4 pack = { (bf16)acc[mf][nf][0], (bf16)acc[mf][nf][1],
                                (bf16)acc[mf][nf][2], (bf16)acc[mf][nf][3] };
                *(bf16x4*)(Vt + ((size_t)(b * NUM_HEADS + h) * HEAD_DIM + d) * SEQ + s) = pack;
            }
    }
}

__global__ __launch_bounds__(256) void gemm_outp(const bf16* __restrict__ at,
                                                 const bf16* __restrict__ woT,
                                                 float* __restrict__ out) {
    __shared__ __attribute__((aligned(16))) bf16 As[BM * BK];
    __shared__ __attribute__((aligned(16))) bf16 Bs[BN * BK];
    int m0 = blockIdx.y * BM, n0 = blockIdx.x * BN;
    f32x4 acc[4][4];
    gemm_core(at, woT, m0, n0, DMODEL, As, Bs, acc);

    int lane = threadIdx.x & 63, wave = threadIdx.x >> 6;
    int wm = (wave >> 1) * 64, wn = (wave & 1) * 64;
    int col0 = n0 + wn + (lane & 15);
    int row0 = m0 + wm + (lane >> 4) * 4;
#pragma unroll
    for (int mf = 0; mf < 4; mf++)
#pragma unroll
        for (int nf = 0; nf < 4; nf++) {
            int n = col0 + nf * 16;
            int mb = row0 + mf * 16;
#pragma unroll
            for (int i2 = 0; i2 < 4; i2++)
                out[(size_t)(mb + i2) * DMODEL + n] = acc[mf][nf][i2];
        }
}

// ---------------- flash attention: KV-split pairs, swapped-QK^T, 32 q-rows ----------------
// grid 2048, block 128 (2 waves). BOTH waves own the SAME 32 q-rows (two 16-row
// fragments sharing every K/V load); they split the causal KV range in half:
// wave0 -> kv tiles [0, nkt/2), wave1 -> [nkt/2, nkt). Partials merged in-block
// via LDS (one barrier, standard 2-accumulator online-softmax merge).
// => 16 waves/CU (4/SIMD) for latency hiding, intra-block imbalance <= 1 iter.
// XCD remap: id&7 = xcd; 4 (b,h) per XCD -> K+V 2MB fits its 4MB L2.
// Diagonal (masked) KV tile always falls in wave1's range.
__global__ __launch_bounds__(128) void attn_kernel(const bf16* __restrict__ Qh, const bf16* __restrict__ Kh,
                                                   const bf16* __restrict__ Vt, bf16* __restrict__ attn) {
    __shared__ __attribute__((aligned(16))) bf16 Pl[2 * 2 * 16 * 64];  // per-wave P tiles (2 frags)
    __shared__ float Om[32 * 65];                                      // wave0 partial O (padded)
    __shared__ float Ml0[32], Ml1[32];                                 // wave0 m, l per row
    int id = blockIdx.x;
    int xcd = id & 7, slot = id >> 3;        // slot 0..255
    int hb = xcd * 4 + (slot >> 6);          // 4 (b,h) per XCD
    int tile = slot & 63;                    // 32-row q tile, 0..63
    int b = hb >> 4, h = hb & 15;
    int t = threadIdx.x, lane = t & 63, wave = t >> 6;
    int l15 = lane & 15, lg = lane >> 4;
    int q0 = tile * 32;
    int nkt = (tile >> 1) + 1;               // total KV tiles of 64
    int split = nkt >> 1;
    int klo = wave ? split : 0;
    int khi = wave ? nkt : split;

    const bf16* Qb = Qh + ((size_t)(b * NUM_HEADS + h) * SEQ) * HEAD_DIM;
    const bf16* Kb = Kh + ((size_t)(b * NUM_HEADS + h) * SEQ) * HEAD_DIM;
    const bf16* Vb = Vt + ((size_t)(b * NUM_HEADS + h) * HEAD_DIM) * SEQ;  // [D][S]

    // Q fragments: frag f covers q rows q0+f*16 .. +15 (pre-scaled by QSCALE)
    bf16x8 qf[2][2];
#pragma unroll
    for (int f = 0; f < 2; f++)
#pragma unroll
        for (int ks = 0; ks < 2; ks++)
            qf[f][ks] = *(const bf16x8*)(Qb + (size_t)(q0 + f * 16 + l15) * HEAD_DIM + ks * 32 + lg * 8);

    f32x4 oacc[2][4];
#pragma unroll
    for (int f = 0; f < 2; f++)
#pragma unroll
        for (int df = 0; df < 4; df++) oacc[f][df] = (f32x4){0.f, 0.f, 0.f, 0.f};
    float mrun[2] = {-1e30f, -1e30f}, lrun[2] = {0.f, 0.f};

    char* Pw = (char*)Pl + wave * 4096;
    int swz = (l15 & 7) << 4;

    for (int kt = klo; kt < khi; kt++) {
        int kv0 = kt * 64;
        // QK^T (swapped): st[f][cf][i] = S[q=q0+f*16+l15][kv = kv0+cf*16+lg*4+i]
        f32x4 st[2][4];
#pragma unroll
        for (int cf = 0; cf < 4; cf++) {
            bf16x8 kfr[2];
#pragma unroll
            for (int ks = 0; ks < 2; ks++)
                kfr[ks] = *(const bf16x8*)(Kb + (size_t)(kv0 + cf * 16 + l15) * HEAD_DIM + ks * 32 + lg * 8);
            st[0][cf] = (f32x4){0.f, 0.f, 0.f, 0.f};
            st[1][cf] = (f32x4){0.f, 0.f, 0.f, 0.f};
            __builtin_amdgcn_s_setprio(1);
#pragma unroll
            for (int ks = 0; ks < 2; ks++) {
                st[0][cf] = MFMA16(kfr[ks], qf[0][ks], st[0][cf]);
                st[1][cf] = MFMA16(kfr[ks], qf[1][ks], st[1][cf]);
            }
            __builtin_amdgcn_s_setprio(0);
        }
        // causal mask: only the global last tile can have kv > q (always in wave1's range)
        if (kt == nkt - 1) {
#pragma unroll
            for (int f = 0; f < 2; f++) {
                int qrow = q0 + f * 16 + l15;
#pragma unroll
                for (int cf = 0; cf < 4; cf++)
#pragma unroll
                    for (int i = 0; i < 4; i++) {
                        int kv = kv0 + cf * 16 + lg * 4 + i;
                        if (kv > qrow) st[f][cf][i] = -1e30f;
                    }
            }
        }
        // softmax per fragment (tree reductions; defer-max T13)
#pragma unroll
        for (int f = 0; f < 2; f++) {
            float m01 = fmaxf(fmaxf(st[f][0][0], st[f][0][1]), fmaxf(st[f][0][2], st[f][0][3]));
            float m23 = fmaxf(fmaxf(st[f][1][0], st[f][1][1]), fmaxf(st[f][1][2], st[f][1][3]));
            float m45 = fmaxf(fmaxf(st[f][2][0], st[f][2][1]), fmaxf(st[f][2][2], st[f][2][3]));
            float m67 = fmaxf(fmaxf(st[f][3][0], st[f][3][1]), fmaxf(st[f][3][2], st[f][3][3]));
            float mx = fmaxf(fmaxf(m01, m23), fmaxf(m45, m67));
            mx = fmaxf(mx, __shfl_xor(mx, 16, 64));
            mx = fmaxf(mx, __shfl_xor(mx, 32, 64));
            if (!__all(mx <= mrun[f] + 8.0f)) {
                float mnew = fmaxf(mrun[f], mx);
                float alpha = fast_exp2(mrun[f] - mnew);
                float av[4];
#pragma unroll
                for (int i = 0; i < 4; i++) av[i] = __shfl(alpha, lg * 4 + i, 64);
#pragma unroll
                for (int df = 0; df < 4; df++)
#pragma unroll
                    for (int i = 0; i < 4; i++) oacc[f][df][i] *= av[i];
                lrun[f] *= alpha;
                mrun[f] = mnew;
            }
            float psc[4];
            bf16x4 pb[4];
#pragma unroll
            for (int cf = 0; cf < 4; cf++) {
                float p0 = fast_exp2(st[f][cf][0] - mrun[f]);
                float p1 = fast_exp2(st[f][cf][1] - mrun[f]);
                float p2 = fast_exp2(st[f][cf][2] - mrun[f]);
                float p3 = fast_exp2(st[f][cf][3] - mrun[f]);
                psc[cf] = (p0 + p1) + (p2 + p3);
                pb[cf][0] = (bf16)p0; pb[cf][1] = (bf16)p1;
                pb[cf][2] = (bf16)p2; pb[cf][3] = (bf16)p3;
            }
            float ps = (psc[0] + psc[1]) + (psc[2] + psc[3]);
            ps += __shfl_xor(ps, 16, 64);
            ps += __shfl_xor(ps, 32, 64);
            lrun[f] += ps;
            // P -> LDS (XOR-swizzled rows); plain C++ so compiler tracks deps
#pragma unroll
            for (int cf = 0; cf < 4; cf++) {
                int off = (l15 * 128 + cf * 32 + lg * 8) ^ swz;
                *(bf16x4*)(Pw + f * 2048 + off) = pb[cf];
            }
        }
        // read P back as PV A-fragments (compiler inserts precise lgkmcnt)
        bf16x8 pa[2][2];
#pragma unroll
        for (int f = 0; f < 2; f++)
#pragma unroll
            for (int ks = 0; ks < 2; ks++) {
                int off = (l15 * 128 + ks * 64 + lg * 16) ^ swz;
                pa[f][ks] = *(const bf16x8*)(Pw + f * 2048 + off);
            }
        // PV: both fragments share each V load
#pragma unroll
        for (int ks = 0; ks < 2; ks++)
#pragma unroll
            for (int df = 0; df < 4; df++) {
                bf16x8 bv = *(const bf16x8*)(Vb + (size_t)(df * 16 + l15) * SEQ + kv0 + ks * 32 + lg * 8);
                __builtin_amdgcn_s_setprio(1);
                oacc[0][df] = MFMA16(pa[0][ks], bv, oacc[0][df]);
                oacc[1][df] = MFMA16(pa[1][ks], bv, oacc[1][df]);
                __builtin_amdgcn_s_setprio(0);
            }
    }

    // ---- in-block merge of the two KV-partials ----
    if (wave == 0) {
        // publish raw partial O, m, l
        if (lane < 16) {
#pragma unroll
            for (int f = 0; f < 2; f++) {
                Ml0[f * 16 + lane] = mrun[f];
                Ml1[f * 16 + lane] = lrun[f];
            }
        }
#pragma unroll
        for (int f = 0; f < 2; f++)
#pragma unroll
            for (int df = 0; df < 4; df++)
#pragma unroll
                for (int i = 0; i < 4; i++)
                    Om[(f * 16 + lg * 4 + i) * 65 + df * 16 + l15] = oacc[f][df][i];
    }
    __syncthreads();
    if (wave == 1) {
#pragma unroll
        for (int f = 0; f < 2; f++) {
            float mAr = Ml0[f * 16 + l15];
            float lAr = Ml1[f * 16 + l15];
            float mstar = fmaxf(mrun[f], mAr);
            float aB = fast_exp2(mrun[f] - mstar);
            float aA = fast_exp2(mAr - mstar);
            float lfin = lrun[f] * aB + lAr * aA;
            float lrec = 1.0f / lfin;
            float aAv[4], aBv[4], lv[4];
#pragma unroll
            for (int i = 0; i < 4; i++) {
                aAv[i] = __shfl(aA, lg * 4 + i, 64);
                aBv[i] = __shfl(aB, lg * 4 + i, 64);
                lv[i]  = __shfl(lrec, lg * 4 + i, 64);
            }
#pragma unroll
            for (int df = 0; df < 4; df++)
#pragma unroll
                for (int i = 0; i < 4; i++) {
                    int qrow = q0 + f * 16 + lg * 4 + i;
                    int d = df * 16 + l15;
                    float oA = Om[(f * 16 + lg * 4 + i) * 65 + d];
                    float o = oacc[f][df][i] * aBv[i] + oA * aAv[i];
                    attn[((size_t)(b * SEQ + qrow)) * DMODEL + h * HEAD_DIM + d] = (bf16)(o * lv[i]);
                }
        }
    }
}

// ---------------- launch ----------------

extern "C" void kernel_launch(void* const* d_in, const int* in_sizes, int n_in,
                              void* d_out, int out_size, void* d_ws, size_t ws_size,
                              hipStream_t stream) {
    const float* x  = (const float*)d_in[0];
    const float* wq = (const float*)d_in[1];
    const float* wk = (const float*)d_in[2];
    const float* wv = (const float*)d_in[3];
    const float* wo = (const float*)d_in[4];
    float* out = (float*)d_out;

    char* w = (char*)d_ws;
    bf16* xb  = (bf16*)(w);                        // 8 MB
    bf16* wqT = (bf16*)(w + (8ull  << 20));        // 2 MB
    bf16* wkT = (bf16*)(w + (10ull << 20));
    bf16* wvT = (bf16*)(w + (12ull << 20));
    bf16* woT = (bf16*)(w + (14ull << 20));
    bf16* Qh  = (bf16*)(w + (16ull << 20));        // 8 MB, [B][H][S][D]
    bf16* Kh  = (bf16*)(w + (24ull << 20));        // 8 MB, [B][H][S][D]
    bf16* Vt  = (bf16*)(w + (32ull << 20));        // 8 MB, [B][H][D][S]
    bf16* at  = (bf16*)(w + (40ull << 20));        // 8 MB  (total 48 MB)

    cvt_f32_bf16<<<(MROWS * DMODEL / 4 + 255) / 256, 256, 0, stream>>>(x, xb, MROWS * DMODEL / 4);
    cvt_trans<<<dim3(16, 16, 4), 256, 0, stream>>>(wq, wk, wv, wo, wqT, wkT, wvT, woT);
    gemm_qkv<<<dim3(DMODEL / BN, MROWS / BM, 3), 256, 0, stream>>>(xb, wqT, wkT, wvT, Qh, Kh, Vt);
    attn_kernel<<<dim3(2048, 1, 1), 128, 0, stream>>>(Qh, Kh, Vt, at);
    gemm_outp<<<dim3(DMODEL / BN, MROWS / BM), 256, 0, stream>>>(at, woT, out);
}

// Round 6
// 145.663 us; speedup vs baseline: 1.4818x; 1.2135x over previous
//
#include <hip/hip_runtime.h>
#include <hip/hip_bf16.h>

#define NUM_HEADS 16
#define HEAD_DIM 64
#define DMODEL 1024
#define SEQ 2048
#define BATCH 2
#define MROWS (BATCH*SEQ)

typedef __bf16 bf16;
typedef __bf16 bf16x4 __attribute__((ext_vector_type(4)));
typedef __bf16 bf16x8 __attribute__((ext_vector_type(8)));
typedef float f32x4 __attribute__((ext_vector_type(4)));

#define MFMA16(a, b, c) __builtin_amdgcn_mfma_f32_16x16x32_bf16((a), (b), (c), 0, 0, 0)

// 0.125 * log2(e): folded into Q so QK^T logits land in exp2 domain
#define QSCALE 0.1803368801111444f

__device__ __forceinline__ float fast_exp2(float x) {
    float r;
    asm("v_exp_f32 %0, %1" : "=v"(r) : "v"(x));
    return r;
}

__device__ __forceinline__ void gld16(const void* g, void* l) {
    __builtin_amdgcn_global_load_lds(
        (const __attribute__((address_space(1))) void*)g,
        (__attribute__((address_space(3))) void*)l, 16, 0, 0);
}

// ---------------- conversion kernels ----------------

__global__ __launch_bounds__(256) void cvt_f32_bf16(const float* __restrict__ in,
                                                    bf16* __restrict__ out, int n4) {
    int i = blockIdx.x * 256 + threadIdx.x;
    if (i >= n4) return;
    float4 v = *(const float4*)(in + (size_t)i * 4);
    bf16x4 o = { (bf16)v.x, (bf16)v.y, (bf16)v.z, (bf16)v.w };
    *(bf16x4*)(out + (size_t)i * 4) = o;
}

// w [1024][1024] f32 -> wT bf16 [1024][1024], wT[n][k] = w[k][n]
__global__ __launch_bounds__(256) void cvt_trans(const float* __restrict__ w0, const float* __restrict__ w1,
                                                 const float* __restrict__ w2, const float* __restrict__ w3,
                                                 bf16* __restrict__ o0, bf16* __restrict__ o1,
                                                 bf16* __restrict__ o2, bf16* __restrict__ o3) {
    const float* w = blockIdx.z == 0 ? w0 : blockIdx.z == 1 ? w1 : blockIdx.z == 2 ? w2 : w3;
    bf16* o = blockIdx.z == 0 ? o0 : blockIdx.z == 1 ? o1 : blockIdx.z == 2 ? o2 : o3;
    __shared__ bf16 tile[64][65];
    int k0 = blockIdx.y * 64, n0 = blockIdx.x * 64;
    int tc = threadIdx.x & 63;
    int tr0 = threadIdx.x >> 6;
#pragma unroll
    for (int i = 0; i < 16; i++) {
        int r = tr0 + i * 4;  // k row
        tile[r][tc] = (bf16)w[(size_t)(k0 + r) * DMODEL + n0 + tc];
    }
    __syncthreads();
#pragma unroll
    for (int i = 0; i < 16; i++) {
        int r = tr0 + i * 4;  // n row of output
        o[(size_t)(n0 + r) * DMODEL + k0 + tc] = tile[tc][r];
    }
}

// ---------------- GEMM core: C[128][128] tile = A[m][k] * Bt[n][k]^T ----------------

#define BM 128
#define BN 128
#define BK 32

__device__ __forceinline__ void gemm_core(const bf16* __restrict__ A, const bf16* __restrict__ Bt,
                                          int m0, int n0, int Kdim,
                                          bf16* As, bf16* Bs, f32x4 acc[4][4]) {
    int t = threadIdx.x;
    int lane = t & 63;
    int wave = t >> 6;
    int wm = (wave >> 1) * 64;
    int wn = (wave & 1) * 64;
#pragma unroll
    for (int mf = 0; mf < 4; mf++)
#pragma unroll
        for (int nf = 0; nf < 4; nf++) acc[mf][nf] = (f32x4){0.f, 0.f, 0.f, 0.f};

    int arow = lane & 15, kg = lane >> 4;

    for (int k0 = 0; k0 < Kdim; k0 += BK) {
        __syncthreads();
#pragma unroll
        for (int it = 0; it < 2; it++) {
            int chunk = it * 256 + t;
            int rr = chunk >> 2, cc = chunk & 3;
            gld16(A + (size_t)(m0 + rr) * Kdim + k0 + cc * 8, As + chunk * 8);
            gld16(Bt + (size_t)(n0 + rr) * Kdim + k0 + cc * 8, Bs + chunk * 8);
        }
        __syncthreads();
        bf16x8 af[4], bfr[4];
#pragma unroll
        for (int mf = 0; mf < 4; mf++)
            af[mf] = *(const bf16x8*)(As + (wm + mf * 16 + arow) * BK + kg * 8);
#pragma unroll
        for (int nf = 0; nf < 4; nf++)
            bfr[nf] = *(const bf16x8*)(Bs + (wn + nf * 16 + arow) * BK + kg * 8);
#pragma unroll
        for (int mf = 0; mf < 4; mf++)
#pragma unroll
            for (int nf = 0; nf < 4; nf++)
                acc[mf][nf] = MFMA16(af[mf], bfr[nf], acc[mf][nf]);
    }
}

// z=0 -> Q head-major [B][H][S][D], pre-scaled by QSCALE; z=1 -> K head-major; z=2 -> V [B][H][D][S]
__global__ __launch_bounds__(256) void gemm_qkv(const bf16* __restrict__ xb,
                                                const bf16* __restrict__ wqT, const bf16* __restrict__ wkT,
                                                const bf16* __restrict__ wvT,
                                                bf16* __restrict__ Qh, bf16* __restrict__ Kh,
                                                bf16* __restrict__ Vt) {
    __shared__ __attribute__((aligned(16))) bf16 As[BM * BK];
    __shared__ __attribute__((aligned(16))) bf16 Bs[BN * BK];
    int z = blockIdx.z;
    const bf16* Bt = z == 0 ? wqT : z == 1 ? wkT : wvT;
    int m0 = blockIdx.y * BM, n0 = blockIdx.x * BN;
    f32x4 acc[4][4];
    gemm_core(xb, Bt, m0, n0, DMODEL, As, Bs, acc);

    int lane = threadIdx.x & 63, wave = threadIdx.x >> 6;
    int wm = (wave >> 1) * 64, wn = (wave & 1) * 64;
    int col0 = n0 + wn + (lane & 15);
    int row0 = m0 + wm + (lane >> 4) * 4;
    if (z < 2) {
        bf16* O = z == 0 ? Qh : Kh;
        float scl = z == 0 ? QSCALE : 1.0f;
#pragma unroll
        for (int mf = 0; mf < 4; mf++)
#pragma unroll
            for (int nf = 0; nf < 4; nf++) {
                int n = col0 + nf * 16;
                int mb = row0 + mf * 16;
                int hh = n >> 6, d = n & 63;
#pragma unroll
                for (int i2 = 0; i2 < 4; i2++) {
                    int m = mb + i2;
                    int bb = m >> 11, s = m & 2047;
                    O[(((size_t)bb * NUM_HEADS + hh) * SEQ + s) * HEAD_DIM + d] =
                        (bf16)(acc[mf][nf][i2] * scl);
                }
            }
    } else {
#pragma unroll
        for (int mf = 0; mf < 4; mf++)
#pragma unroll
            for (int nf = 0; nf < 4; nf++) {
                int n = col0 + nf * 16;
                int m = row0 + mf * 16;
                int b = m >> 11, s = m & 2047;
                int h = n >> 6, d = n & 63;
                bf16x4 pack = { (bf16)acc[mf][nf][0], (bf16)acc[mf][nf][1],
                                (bf16)acc[mf][nf][2], (bf16)acc[mf][nf][3] };
                *(bf16x4*)(Vt + ((size_t)(b * NUM_HEADS + h) * HEAD_DIM + d) * SEQ + s) = pack;
            }
    }
}

__global__ __launch_bounds__(256) void gemm_outp(const bf16* __restrict__ at,
                                                 const bf16* __restrict__ woT,
                                                 float* __restrict__ out) {
    __shared__ __attribute__((aligned(16))) bf16 As[BM * BK];
    __shared__ __attribute__((aligned(16))) bf16 Bs[BN * BK];
    int m0 = blockIdx.y * BM, n0 = blockIdx.x * BN;
    f32x4 acc[4][4];
    gemm_core(at, woT, m0, n0, DMODEL, As, Bs, acc);

    int lane = threadIdx.x & 63, wave = threadIdx.x >> 6;
    int wm = (wave >> 1) * 64, wn = (wave & 1) * 64;
    int col0 = n0 + wn + (lane & 15);
    int row0 = m0 + wm + (lane >> 4) * 4;
#pragma unroll
    for (int mf = 0; mf < 4; mf++)
#pragma unroll
        for (int nf = 0; nf < 4; nf++) {
            int n = col0 + nf * 16;
            int mb = row0 + mf * 16;
#pragma unroll
            for (int i2 = 0; i2 < 4; i2++)
                out[(size_t)(mb + i2) * DMODEL + n] = acc[mf][nf][i2];
        }
}

// ---------------- flash attention: cooperative LDS-staged KV, QBLK=128 ----------------
// grid 512, block 256 (4 waves). Block owns 128 q-rows (wave w: rows q0+w*32 as
// two 16-row frags, same math as before). KVBLK=64. K and V tiles double-buffered
// in LDS via global_load_lds(16B): stage(kt+1) issued BEFORE compute(kt), so
// HBM/L2 latency hides under QK+softmax+PV (T3 minimum 2-phase). K/V LDS is
// XOR-swizzled (T2): linear LDS dest + inverse-swizzled GLOBAL source at stage,
// swizzled ds_read at consume (both-sides rule). K/V loads amortize 4x across
// waves. All waves stage+barrier every tile (uniform barrier count); waves
// compute only tiles their q-range needs. XCD-bijective id map: 4 (b,h)/XCD.
__global__ __launch_bounds__(256) void attn_kernel(const bf16* __restrict__ Qh, const bf16* __restrict__ Kh,
                                                   const bf16* __restrict__ Vt, bf16* __restrict__ attn) {
    __shared__ __attribute__((aligned(16))) bf16 Kl[2 * 64 * 64];      // 2 x 8KB, swizzled [kv][d]
    __shared__ __attribute__((aligned(16))) bf16 Vl[2 * 64 * 64];      // 2 x 8KB, swizzled [d][kv]
    __shared__ __attribute__((aligned(16))) bf16 Pl[4 * 2 * 16 * 64];  // per-wave P (2 frags x 2KB)
    int id = blockIdx.x;
    int xcd = id & 7, slot = id >> 3;        // slot 0..63
    int hb = xcd * 4 + (slot >> 4);          // 4 (b,h) per XCD
    int qt = slot & 15;                      // q-tile of 128 rows
    int b = hb >> 4, h = hb & 15;
    int t = threadIdx.x, lane = t & 63, wave = t >> 6;
    int l15 = lane & 15, lg = lane >> 4;
    int q0 = qt * 128;
    int q0w = q0 + wave * 32;                // this wave's 32 q-rows
    int nkt = 2 * qt + 2;                    // KV tiles of 64 for the whole block

    const bf16* Qb = Qh + ((size_t)(b * NUM_HEADS + h) * SEQ) * HEAD_DIM;
    const bf16* Kb = Kh + ((size_t)(b * NUM_HEADS + h) * SEQ) * HEAD_DIM;
    const bf16* Vb = Vt + ((size_t)(b * NUM_HEADS + h) * HEAD_DIM) * SEQ;  // [D][S]

    // Q fragments (pre-scaled by QSCALE in GEMM epilogue)
    bf16x8 qf[2][2];
#pragma unroll
    for (int f = 0; f < 2; f++)
#pragma unroll
        for (int ks = 0; ks < 2; ks++)
            qf[f][ks] = *(const bf16x8*)(Qb + (size_t)(q0w + f * 16 + l15) * HEAD_DIM + ks * 32 + lg * 8);

    f32x4 oacc[2][4];
#pragma unroll
    for (int f = 0; f < 2; f++)
#pragma unroll
        for (int df = 0; df < 4; df++) oacc[f][df] = (f32x4){0.f, 0.f, 0.f, 0.f};
    float mrun[2] = {-1e30f, -1e30f}, lrun[2] = {0.f, 0.f};

    char* Pw = (char*)Pl + wave * 4096;
    int swz = (l15 & 7) << 4;

    // stage one 64x64 K tile + V tile into LDS buffer bufi, inverse-swizzled source.
    // chunk c (16B): LDS[c*16] holds global linear offset L = c*16 ^ ((c>>3 & 7)<<4)
    // => read side applies  off ^ ((row&7)<<4)  and gets linear data.
    auto STAGE = [&](int bufi, int kv0n) {
#pragma unroll
        for (int j = 0; j < 2; j++) {
            int c = (wave * 2 + j) * 64 + lane;          // 0..511
            int L = (c * 16) ^ (((c >> 3) & 7) << 4);
            int row = c >> 3, cole = (L & 127) >> 1;     // row 0..63, element col 0..63
            gld16(Kb + (size_t)(kv0n + row) * HEAD_DIM + cole,
                  (char*)Kl + (size_t)bufi * 8192 + c * 16);
            gld16(Vb + (size_t)row * SEQ + kv0n + cole,
                  (char*)Vl + (size_t)bufi * 8192 + c * 16);
        }
    };

    STAGE(0, 0);
    __syncthreads();
    int buf = 0;

    for (int kt = 0; kt < nkt; kt++) {
        int kv0 = kt * 64;
        if (kt + 1 < nkt) STAGE(buf ^ 1, kv0 + 64);   // async prefetch, hidden under compute

        if (kv0 <= q0w + 31) {                         // this wave needs this tile
            const char* KL = (const char*)Kl + (size_t)buf * 8192;
            const char* VL = (const char*)Vl + (size_t)buf * 8192;
            // QK^T (swapped): st[f][cf][i] = S[q=q0w+f*16+l15][kv = kv0+cf*16+lg*4+i]
            f32x4 st[2][4];
#pragma unroll
            for (int cf = 0; cf < 4; cf++) {
                bf16x8 kfr[2];
#pragma unroll
                for (int ks = 0; ks < 2; ks++) {
                    int off = ((cf * 16 + l15) * 128 + ks * 64 + lg * 16) ^ swz;
                    kfr[ks] = *(const bf16x8*)(KL + off);
                }
                st[0][cf] = (f32x4){0.f, 0.f, 0.f, 0.f};
                st[1][cf] = (f32x4){0.f, 0.f, 0.f, 0.f};
                __builtin_amdgcn_s_setprio(1);
#pragma unroll
                for (int ks = 0; ks < 2; ks++) {
                    st[0][cf] = MFMA16(kfr[ks], qf[0][ks], st[0][cf]);
                    st[1][cf] = MFMA16(kfr[ks], qf[1][ks], st[1][cf]);
                }
                __builtin_amdgcn_s_setprio(0);
            }
            // causal mask on tiles overlapping the diagonal
            if (kv0 + 63 > q0w) {
#pragma unroll
                for (int f = 0; f < 2; f++) {
                    int qrow = q0w + f * 16 + l15;
#pragma unroll
                    for (int cf = 0; cf < 4; cf++)
#pragma unroll
                        for (int i = 0; i < 4; i++) {
                            int kv = kv0 + cf * 16 + lg * 4 + i;
                            if (kv > qrow) st[f][cf][i] = -1e30f;
                        }
                }
            }
            // softmax per fragment (tree reductions; defer-max T13)
#pragma unroll
            for (int f = 0; f < 2; f++) {
                float m01 = fmaxf(fmaxf(st[f][0][0], st[f][0][1]), fmaxf(st[f][0][2], st[f][0][3]));
                float m23 = fmaxf(fmaxf(st[f][1][0], st[f][1][1]), fmaxf(st[f][1][2], st[f][1][3]));
                float m45 = fmaxf(fmaxf(st[f][2][0], st[f][2][1]), fmaxf(st[f][2][2], st[f][2][3]));
                float m67 = fmaxf(fmaxf(st[f][3][0], st[f][3][1]), fmaxf(st[f][3][2], st[f][3][3]));
                float mx = fmaxf(fmaxf(m01, m23), fmaxf(m45, m67));
                mx = fmaxf(mx, __shfl_xor(mx, 16, 64));
                mx = fmaxf(mx, __shfl_xor(mx, 32, 64));
                if (!__all(mx <= mrun[f] + 8.0f)) {
                    float mnew = fmaxf(mrun[f], mx);
                    float alpha = fast_exp2(mrun[f] - mnew);
                    float av[4];
#pragma unroll
                    for (int i = 0; i < 4; i++) av[i] = __shfl(alpha, lg * 4 + i, 64);
#pragma unroll
                    for (int df = 0; df < 4; df++)
#pragma unroll
                        for (int i = 0; i < 4; i++) oacc[f][df][i] *= av[i];
                    lrun[f] *= alpha;
                    mrun[f] = mnew;
                }
                float psc[4];
                bf16x4 pb[4];
#pragma unroll
                for (int cf = 0; cf < 4; cf++) {
                    float p0 = fast_exp2(st[f][cf][0] - mrun[f]);
                    float p1 = fast_exp2(st[f][cf][1] - mrun[f]);
                    float p2 = fast_exp2(st[f][cf][2] - mrun[f]);
                    float p3 = fast_exp2(st[f][cf][3] - mrun[f]);
                    psc[cf] = (p0 + p1) + (p2 + p3);
                    pb[cf][0] = (bf16)p0; pb[cf][1] = (bf16)p1;
                    pb[cf][2] = (bf16)p2; pb[cf][3] = (bf16)p3;
                }
                float ps = (psc[0] + psc[1]) + (psc[2] + psc[3]);
                ps += __shfl_xor(ps, 16, 64);
                ps += __shfl_xor(ps, 32, 64);
                lrun[f] += ps;
                // P -> per-wave LDS (XOR-swizzled rows)
#pragma unroll
                for (int cf = 0; cf < 4; cf++) {
                    int off = (l15 * 128 + cf * 32 + lg * 8) ^ swz;
                    *(bf16x4*)(Pw + f * 2048 + off) = pb[cf];
                }
            }
            // read P back as PV A-fragments
            bf16x8 pa[2][2];
#pragma unroll
            for (int f = 0; f < 2; f++)
#pragma unroll
                for (int ks = 0; ks < 2; ks++) {
                    int off = (l15 * 128 + ks * 64 + lg * 16) ^ swz;
                    pa[f][ks] = *(const bf16x8*)(Pw + f * 2048 + off);
                }
            // PV: V from LDS (swizzled [d][kv]); both frags share each V read
#pragma unroll
            for (int ks = 0; ks < 2; ks++)
#pragma unroll
                for (int df = 0; df < 4; df++) {
                    int off = ((df * 16 + l15) * 128 + ks * 64 + lg * 16) ^ swz;
                    bf16x8 bv = *(const bf16x8*)(VL + off);
                    __builtin_amdgcn_s_setprio(1);
                    oacc[0][df] = MFMA16(pa[0][ks], bv, oacc[0][df]);
                    oacc[1][df] = MFMA16(pa[1][ks], bv, oacc[1][df]);
                    __builtin_amdgcn_s_setprio(0);
                }
        }
        __syncthreads();   // stage(kt+1) complete; safe to flip buffers
        buf ^= 1;
    }

    // epilogue: divide row q by lrun; stats live at lane q (q<16)
#pragma unroll
    for (int f = 0; f < 2; f++) {
        float lrec = 1.0f / lrun[f];
        float lv[4];
#pragma unroll
        for (int i = 0; i < 4; i++) lv[i] = __shfl(lrec, lg * 4 + i, 64);
#pragma unroll
        for (int df = 0; df < 4; df++)
#pragma unroll
            for (int i = 0; i < 4; i++) {
                int qrow = q0w + f * 16 + lg * 4 + i;
                int d = df * 16 + l15;
                attn[((size_t)(b * SEQ + qrow)) * DMODEL + h * HEAD_DIM + d] = (bf16)(oacc[f][df][i] * lv[i]);
            }
    }
}

// ---------------- launch ----------------

extern "C" void kernel_launch(void* const* d_in, const int* in_sizes, int n_in,
                              void* d_out, int out_size, void* d_ws, size_t ws_size,
                              hipStream_t stream) {
    const float* x  = (const float*)d_in[0];
    const float* wq = (const float*)d_in[1];
    const float* wk = (const float*)d_in[2];
    const float* wv = (const float*)d_in[3];
    const float* wo = (const float*)d_in[4];
    float* out = (float*)d_out;

    char* w = (char*)d_ws;
    bf16* xb  = (bf16*)(w);                        // 8 MB
    bf16* wqT = (bf16*)(w + (8ull  << 20));        // 2 MB
    bf16* wkT = (bf16*)(w + (10ull << 20));
    bf16* wvT = (bf16*)(w + (12ull << 20));
    bf16* woT = (bf16*)(w + (14ull << 20));
    bf16* Qh  = (bf16*)(w + (16ull << 20));        // 8 MB, [B][H][S][D]
    bf16* Kh  = (bf16*)(w + (24ull << 20));        // 8 MB, [B][H][S][D]
    bf16* Vt  = (bf16*)(w + (32ull << 20));        // 8 MB, [B][H][D][S]
    bf16* at  = (bf16*)(w + (40ull << 20));        // 8 MB  (total 48 MB)

    cvt_f32_bf16<<<(MROWS * DMODEL / 4 + 255) / 256, 256, 0, stream>>>(x, xb, MROWS * DMODEL / 4);
    cvt_trans<<<dim3(16, 16, 4), 256, 0, stream>>>(wq, wk, wv, wo, wqT, wkT, wvT, woT);
    gemm_qkv<<<dim3(DMODEL / BN, MROWS / BM, 3), 256, 0, stream>>>(xb, wqT, wkT, wvT, Qh, Kh, Vt);
    attn_kernel<<<dim3(512, 1, 1), 256, 0, stream>>>(Qh, Kh, Vt, at);
    gemm_outp<<<dim3(DMODEL / BN, MROWS / BM), 256, 0, stream>>>(at, woT, out);
}

// Round 7
// 131.375 us; speedup vs baseline: 1.6430x; 1.1088x over previous
//
#include <hip/hip_runtime.h>
#include <hip/hip_bf16.h>

#define NUM_HEADS 16
#define HEAD_DIM 64
#define DMODEL 1024
#define SEQ 2048
#define BATCH 2
#define MROWS (BATCH*SEQ)

typedef __bf16 bf16;
typedef __bf16 bf16x4 __attribute__((ext_vector_type(4)));
typedef __bf16 bf16x8 __attribute__((ext_vector_type(8)));
typedef float f32x4 __attribute__((ext_vector_type(4)));

#define MFMA16(a, b, c) __builtin_amdgcn_mfma_f32_16x16x32_bf16((a), (b), (c), 0, 0, 0)

// 0.125 * log2(e): folded into Q so QK^T logits land in exp2 domain
#define QSCALE 0.1803368801111444f

__device__ __forceinline__ float fast_exp2(float x) {
    float r;
    asm("v_exp_f32 %0, %1" : "=v"(r) : "v"(x));
    return r;
}

__device__ __forceinline__ void gld16(const void* g, void* l) {
    __builtin_amdgcn_global_load_lds(
        (const __attribute__((address_space(1))) void*)g,
        (__attribute__((address_space(3))) void*)l, 16, 0, 0);
}

// ---------------- conversion kernels ----------------

__global__ __launch_bounds__(256) void cvt_f32_bf16(const float* __restrict__ in,
                                                    bf16* __restrict__ out, int n4) {
    int i = blockIdx.x * 256 + threadIdx.x;
    if (i >= n4) return;
    float4 v = *(const float4*)(in + (size_t)i * 4);
    bf16x4 o = { (bf16)v.x, (bf16)v.y, (bf16)v.z, (bf16)v.w };
    *(bf16x4*)(out + (size_t)i * 4) = o;
}

// w [1024][1024] f32 -> wT bf16 [1024][1024], wT[n][k] = w[k][n]
__global__ __launch_bounds__(256) void cvt_trans(const float* __restrict__ w0, const float* __restrict__ w1,
                                                 const float* __restrict__ w2, const float* __restrict__ w3,
                                                 bf16* __restrict__ o0, bf16* __restrict__ o1,
                                                 bf16* __restrict__ o2, bf16* __restrict__ o3) {
    const float* w = blockIdx.z == 0 ? w0 : blockIdx.z == 1 ? w1 : blockIdx.z == 2 ? w2 : w3;
    bf16* o = blockIdx.z == 0 ? o0 : blockIdx.z == 1 ? o1 : blockIdx.z == 2 ? o2 : o3;
    __shared__ bf16 tile[64][65];
    int k0 = blockIdx.y * 64, n0 = blockIdx.x * 64;
    int tc = threadIdx.x & 63;
    int tr0 = threadIdx.x >> 6;
#pragma unroll
    for (int i = 0; i < 16; i++) {
        int r = tr0 + i * 4;  // k row
        tile[r][tc] = (bf16)w[(size_t)(k0 + r) * DMODEL + n0 + tc];
    }
    __syncthreads();
#pragma unroll
    for (int i = 0; i < 16; i++) {
        int r = tr0 + i * 4;  // n row of output
        o[(size_t)(n0 + r) * DMODEL + k0 + tc] = tile[tc][r];
    }
}

// ---------------- GEMM core: C[128][128] tile = A[m][k] * Bt[n][k]^T ----------------

#define BM 128
#define BN 128
#define BK 32

__device__ __forceinline__ void gemm_core(const bf16* __restrict__ A, const bf16* __restrict__ Bt,
                                          int m0, int n0, int Kdim,
                                          bf16* As, bf16* Bs, f32x4 acc[4][4]) {
    int t = threadIdx.x;
    int lane = t & 63;
    int wave = t >> 6;
    int wm = (wave >> 1) * 64;
    int wn = (wave & 1) * 64;
#pragma unroll
    for (int mf = 0; mf < 4; mf++)
#pragma unroll
        for (int nf = 0; nf < 4; nf++) acc[mf][nf] = (f32x4){0.f, 0.f, 0.f, 0.f};

    int arow = lane & 15, kg = lane >> 4;

    for (int k0 = 0; k0 < Kdim; k0 += BK) {
        __syncthreads();
#pragma unroll
        for (int it = 0; it < 2; it++) {
            int chunk = it * 256 + t;
            int rr = chunk >> 2, cc = chunk & 3;
            gld16(A + (size_t)(m0 + rr) * Kdim + k0 + cc * 8, As + chunk * 8);
            gld16(Bt + (size_t)(n0 + rr) * Kdim + k0 + cc * 8, Bs + chunk * 8);
        }
        __syncthreads();
        bf16x8 af[4], bfr[4];
#pragma unroll
        for (int mf = 0; mf < 4; mf++)
            af[mf] = *(const bf16x8*)(As + (wm + mf * 16 + arow) * BK + kg * 8);
#pragma unroll
        for (int nf = 0; nf < 4; nf++)
            bfr[nf] = *(const bf16x8*)(Bs + (wn + nf * 16 + arow) * BK + kg * 8);
#pragma unroll
        for (int mf = 0; mf < 4; mf++)
#pragma unroll
            for (int nf = 0; nf < 4; nf++)
                acc[mf][nf] = MFMA16(af[mf], bfr[nf], acc[mf][nf]);
    }
}

// z=0 -> Q head-major [B][H][S][D], pre-scaled by QSCALE; z=1 -> K head-major; z=2 -> V [B][H][D][S]
__global__ __launch_bounds__(256) void gemm_qkv(const bf16* __restrict__ xb,
                                                const bf16* __restrict__ wqT, const bf16* __restrict__ wkT,
                                                const bf16* __restrict__ wvT,
                                                bf16* __restrict__ Qh, bf16* __restrict__ Kh,
                                                bf16* __restrict__ Vt) {
    __shared__ __attribute__((aligned(16))) bf16 As[BM * BK];
    __shared__ __attribute__((aligned(16))) bf16 Bs[BN * BK];
    int z = blockIdx.z;
    const bf16* Bt = z == 0 ? wqT : z == 1 ? wkT : wvT;
    int m0 = blockIdx.y * BM, n0 = blockIdx.x * BN;
    f32x4 acc[4][4];
    gemm_core(xb, Bt, m0, n0, DMODEL, As, Bs, acc);

    int lane = threadIdx.x & 63, wave = threadIdx.x >> 6;
    int wm = (wave >> 1) * 64, wn = (wave & 1) * 64;
    int col0 = n0 + wn + (lane & 15);
    int row0 = m0 + wm + (lane >> 4) * 4;
    if (z < 2) {
        bf16* O = z == 0 ? Qh : Kh;
        float scl = z == 0 ? QSCALE : 1.0f;
#pragma unroll
        for (int mf = 0; mf < 4; mf++)
#pragma unroll
            for (int nf = 0; nf < 4; nf++) {
                int n = col0 + nf * 16;
                int mb = row0 + mf * 16;
                int hh = n >> 6, d = n & 63;
#pragma unroll
                for (int i2 = 0; i2 < 4; i2++) {
                    int m = mb + i2;
                    int bb = m >> 11, s = m & 2047;
                    O[(((size_t)bb * NUM_HEADS + hh) * SEQ + s) * HEAD_DIM + d] =
                        (bf16)(acc[mf][nf][i2] * scl);
                }
            }
    } else {
#pragma unroll
        for (int mf = 0; mf < 4; mf++)
#pragma unroll
            for (int nf = 0; nf < 4; nf++) {
                int n = col0 + nf * 16;
                int m = row0 + mf * 16;
                int b = m >> 11, s = m & 2047;
                int h = n >> 6, d = n & 63;
                bf16x4 pack = { (bf16)acc[mf][nf][0], (bf16)acc[mf][nf][1],
                                (bf16)acc[mf][nf][2], (bf16)acc[mf][nf][3] };
                *(bf16x4*)(Vt + ((size_t)(b * NUM_HEADS + h) * HEAD_DIM + d) * SEQ + s) = pack;
            }
    }
}

__global__ __launch_bounds__(256) void gemm_outp(const bf16* __restrict__ at,
                                                 const bf16* __restrict__ woT,
                                                 float* __restrict__ out) {
    __shared__ __attribute__((aligned(16))) bf16 As[BM * BK];
    __shared__ __attribute__((aligned(16))) bf16 Bs[BN * BK];
    int m0 = blockIdx.y * BM, n0 = blockIdx.x * BN;
    f32x4 acc[4][4];
    gemm_core(at, woT, m0, n0, DMODEL, As, Bs, acc);

    int lane = threadIdx.x & 63, wave = threadIdx.x >> 6;
    int wm = (wave >> 1) * 64, wn = (wave & 1) * 64;
    int col0 = n0 + wn + (lane & 15);
    int row0 = m0 + wm + (lane >> 4) * 4;
#pragma unroll
    for (int mf = 0; mf < 4; mf++)
#pragma unroll
        for (int nf = 0; nf < 4; nf++) {
            int n = col0 + nf * 16;
            int mb = row0 + mf * 16;
#pragma unroll
            for (int i2 = 0; i2 < 4; i2++)
                out[(size_t)(mb + i2) * DMODEL + n] = acc[mf][nf][i2];
        }
}

// ---------------- flash attention: LDS-staged KV, QBLK=64, 4 blocks/CU ----------------
// grid 1024, block 128 (2 waves x 32 q-rows as two 16-row frags). KVBLK=64,
// K/V double-buffered in LDS (global_load_lds 16B, XOR-swizzled via inverse-
// swizzled global source). LDS = 16K + 16K + 8K P = 40KB -> 4 blocks/CU:
// 4 independent barrier groups + 4 staging streams per CU (vs 2 in R6).
// Per-CU balance BY CONSTRUCTION: under round-robin dispatch the 4 co-resident
// blocks (id stride 256 => same s, bh4 0..3) get qt {u, 31-u, u^16, 31-(u^16)}
// -> exactly 66 KV-iters per CU. XCD map: id&7 = xcd, 4 (b,h)/XCD (K+V 2MB in L2).
__global__ __launch_bounds__(128) void attn_kernel(const bf16* __restrict__ Qh, const bf16* __restrict__ Kh,
                                                   const bf16* __restrict__ Vt, bf16* __restrict__ attn) {
    __shared__ __attribute__((aligned(16))) bf16 Kl[2 * 64 * 64];      // 2 x 8KB, swizzled [kv][d]
    __shared__ __attribute__((aligned(16))) bf16 Vl[2 * 64 * 64];      // 2 x 8KB, swizzled [d][kv]
    __shared__ __attribute__((aligned(16))) bf16 Pl[2 * 2 * 16 * 64];  // per-wave P (2 frags x 2KB)
    int id = blockIdx.x;
    int xcd = id & 7, slot = id >> 3;        // slot 0..127
    int bh4 = slot >> 5;                     // head index within XCD, 0..3
    int s = slot & 31;
    int u = (bh4 & 2) ? ((s + 16) & 31) : s;
    int qt = (bh4 & 1) ? (31 - u) : u;       // q-tile of 64 rows, bijective per bh4
    int hb = xcd * 4 + bh4;
    int b = hb >> 4, h = hb & 15;
    int t = threadIdx.x, lane = t & 63, wave = t >> 6;
    int l15 = lane & 15, lg = lane >> 4;
    int q0 = qt * 64;
    int q0w = q0 + wave * 32;                // this wave's 32 q-rows
    int nkt = qt + 1;                        // KV tiles of 64

    const bf16* Qb = Qh + ((size_t)(b * NUM_HEADS + h) * SEQ) * HEAD_DIM;
    const bf16* Kb = Kh + ((size_t)(b * NUM_HEADS + h) * SEQ) * HEAD_DIM;
    const bf16* Vb = Vt + ((size_t)(b * NUM_HEADS + h) * HEAD_DIM) * SEQ;  // [D][S]

    // Q fragments (pre-scaled by QSCALE in GEMM epilogue)
    bf16x8 qf[2][2];
#pragma unroll
    for (int f = 0; f < 2; f++)
#pragma unroll
        for (int ks = 0; ks < 2; ks++)
            qf[f][ks] = *(const bf16x8*)(Qb + (size_t)(q0w + f * 16 + l15) * HEAD_DIM + ks * 32 + lg * 8);

    f32x4 oacc[2][4];
#pragma unroll
    for (int f = 0; f < 2; f++)
#pragma unroll
        for (int df = 0; df < 4; df++) oacc[f][df] = (f32x4){0.f, 0.f, 0.f, 0.f};
    float mrun[2] = {-1e30f, -1e30f}, lrun[2] = {0.f, 0.f};

    char* Pw = (char*)Pl + wave * 4096;
    int swz = (l15 & 7) << 4;

    // stage one 64x64 K tile + V tile into LDS buffer bufi, inverse-swizzled source.
    // chunk c (16B): LDS[c*16] holds global linear offset L = c*16 ^ ((c>>3 & 7)<<4)
    // => read side applies  off ^ ((row&7)<<4)  and gets linear data.
    auto STAGE = [&](int bufi, int kv0n) {
#pragma unroll
        for (int j = 0; j < 4; j++) {
            int c = j * 128 + t;                         // 0..511
            int L = (c * 16) ^ (((c >> 3) & 7) << 4);
            int row = c >> 3, cole = (L & 127) >> 1;     // row 0..63, element col 0..63
            gld16(Kb + (size_t)(kv0n + row) * HEAD_DIM + cole,
                  (char*)Kl + (size_t)bufi * 8192 + c * 16);
            gld16(Vb + (size_t)row * SEQ + kv0n + cole,
                  (char*)Vl + (size_t)bufi * 8192 + c * 16);
        }
    };

    STAGE(0, 0);
    __syncthreads();
    int buf = 0;

    for (int kt = 0; kt < nkt; kt++) {
        int kv0 = kt * 64;
        if (kt + 1 < nkt) STAGE(buf ^ 1, kv0 + 64);   // async prefetch, hidden under compute

        const char* KL = (const char*)Kl + (size_t)buf * 8192;
        const char* VL = (const char*)Vl + (size_t)buf * 8192;
        // QK^T (swapped): st[f][cf][i] = S[q=q0w+f*16+l15][kv = kv0+cf*16+lg*4+i]
        f32x4 st[2][4];
        __builtin_amdgcn_s_setprio(1);
#pragma unroll
        for (int cf = 0; cf < 4; cf++) {
            bf16x8 kfr[2];
#pragma unroll
            for (int ks = 0; ks < 2; ks++) {
                int off = ((cf * 16 + l15) * 128 + ks * 64 + lg * 16) ^ swz;
                kfr[ks] = *(const bf16x8*)(KL + off);
            }
            st[0][cf] = (f32x4){0.f, 0.f, 0.f, 0.f};
            st[1][cf] = (f32x4){0.f, 0.f, 0.f, 0.f};
#pragma unroll
            for (int ks = 0; ks < 2; ks++) {
                st[0][cf] = MFMA16(kfr[ks], qf[0][ks], st[0][cf]);
                st[1][cf] = MFMA16(kfr[ks], qf[1][ks], st[1][cf]);
            }
        }
        __builtin_amdgcn_s_setprio(0);
        // causal mask: only the last tile overlaps the diagonal (for both waves)
        if (kt == nkt - 1) {
#pragma unroll
            for (int f = 0; f < 2; f++) {
                int qrow = q0w + f * 16 + l15;
#pragma unroll
                for (int cf = 0; cf < 4; cf++)
#pragma unroll
                    for (int i = 0; i < 4; i++) {
                        int kv = kv0 + cf * 16 + lg * 4 + i;
                        if (kv > qrow) st[f][cf][i] = -1e30f;
                    }
            }
        }
        // softmax per fragment (tree reductions; defer-max T13)
#pragma unroll
        for (int f = 0; f < 2; f++) {
            float m01 = fmaxf(fmaxf(st[f][0][0], st[f][0][1]), fmaxf(st[f][0][2], st[f][0][3]));
            float m23 = fmaxf(fmaxf(st[f][1][0], st[f][1][1]), fmaxf(st[f][1][2], st[f][1][3]));
            float m45 = fmaxf(fmaxf(st[f][2][0], st[f][2][1]), fmaxf(st[f][2][2], st[f][2][3]));
            float m67 = fmaxf(fmaxf(st[f][3][0], st[f][3][1]), fmaxf(st[f][3][2], st[f][3][3]));
            float mx = fmaxf(fmaxf(m01, m23), fmaxf(m45, m67));
            mx = fmaxf(mx, __shfl_xor(mx, 16, 64));
            mx = fmaxf(mx, __shfl_xor(mx, 32, 64));
            if (!__all(mx <= mrun[f] + 8.0f)) {
                float mnew = fmaxf(mrun[f], mx);
                float alpha = fast_exp2(mrun[f] - mnew);
                float av[4];
#pragma unroll
                for (int i = 0; i < 4; i++) av[i] = __shfl(alpha, lg * 4 + i, 64);
#pragma unroll
                for (int df = 0; df < 4; df++)
#pragma unroll
                    for (int i = 0; i < 4; i++) oacc[f][df][i] *= av[i];
                lrun[f] *= alpha;
                mrun[f] = mnew;
            }
            float psc[4];
            bf16x4 pb[4];
#pragma unroll
            for (int cf = 0; cf < 4; cf++) {
                float p0 = fast_exp2(st[f][cf][0] - mrun[f]);
                float p1 = fast_exp2(st[f][cf][1] - mrun[f]);
                float p2 = fast_exp2(st[f][cf][2] - mrun[f]);
                float p3 = fast_exp2(st[f][cf][3] - mrun[f]);
                psc[cf] = (p0 + p1) + (p2 + p3);
                pb[cf][0] = (bf16)p0; pb[cf][1] = (bf16)p1;
                pb[cf][2] = (bf16)p2; pb[cf][3] = (bf16)p3;
            }
            float ps = (psc[0] + psc[1]) + (psc[2] + psc[3]);
            ps += __shfl_xor(ps, 16, 64);
            ps += __shfl_xor(ps, 32, 64);
            lrun[f] += ps;
            // P -> per-wave LDS (XOR-swizzled rows)
#pragma unroll
            for (int cf = 0; cf < 4; cf++) {
                int off = (l15 * 128 + cf * 32 + lg * 8) ^ swz;
                *(bf16x4*)(Pw + f * 2048 + off) = pb[cf];
            }
        }
        // read P back as PV A-fragments
        bf16x8 pa[2][2];
#pragma unroll
        for (int f = 0; f < 2; f++)
#pragma unroll
            for (int ks = 0; ks < 2; ks++) {
                int off = (l15 * 128 + ks * 64 + lg * 16) ^ swz;
                pa[f][ks] = *(const bf16x8*)(Pw + f * 2048 + off);
            }
        // PV: V from LDS (swizzled [d][kv]); both frags share each V read
        __builtin_amdgcn_s_setprio(1);
#pragma unroll
        for (int ks = 0; ks < 2; ks++)
#pragma unroll
            for (int df = 0; df < 4; df++) {
                int off = ((df * 16 + l15) * 128 + ks * 64 + lg * 16) ^ swz;
                bf16x8 bv = *(const bf16x8*)(VL + off);
                oacc[0][df] = MFMA16(pa[0][ks], bv, oacc[0][df]);
                oacc[1][df] = MFMA16(pa[1][ks], bv, oacc[1][df]);
            }
        __builtin_amdgcn_s_setprio(0);

        __syncthreads();   // stage(kt+1) complete; safe to flip buffers
        buf ^= 1;
    }

    // epilogue: divide row q by lrun; stats live at lane q (q<16)
#pragma unroll
    for (int f = 0; f < 2; f++) {
        float lrec = 1.0f / lrun[f];
        float lv[4];
#pragma unroll
        for (int i = 0; i < 4; i++) lv[i] = __shfl(lrec, lg * 4 + i, 64);
#pragma unroll
        for (int df = 0; df < 4; df++)
#pragma unroll
            for (int i = 0; i < 4; i++) {
                int qrow = q0w + f * 16 + lg * 4 + i;
                int d = df * 16 + l15;
                attn[((size_t)(b * SEQ + qrow)) * DMODEL + h * HEAD_DIM + d] = (bf16)(oacc[f][df][i] * lv[i]);
            }
    }
}

// ---------------- launch ----------------

extern "C" void kernel_launch(void* const* d_in, const int* in_sizes, int n_in,
                              void* d_out, int out_size, void* d_ws, size_t ws_size,
                              hipStream_t stream) {
    const float* x  = (const float*)d_in[0];
    const float* wq = (const float*)d_in[1];
    const float* wk = (const float*)d_in[2];
    const float* wv = (const float*)d_in[3];
    const float* wo = (const float*)d_in[4];
    float* out = (float*)d_out;

    char* w = (char*)d_ws;
    bf16* xb  = (bf16*)(w);                        // 8 MB
    bf16* wqT = (bf16*)(w + (8ull  << 20));        // 2 MB
    bf16* wkT = (bf16*)(w + (10ull << 20));
    bf16* wvT = (bf16*)(w + (12ull << 20));
    bf16* woT = (bf16*)(w + (14ull << 20));
    bf16* Qh  = (bf16*)(w + (16ull << 20));        // 8 MB, [B][H][S][D]
    bf16* Kh  = (bf16*)(w + (24ull << 20));        // 8 MB, [B][H][S][D]
    bf16* Vt  = (bf16*)(w + (32ull << 20));        // 8 MB, [B][H][D][S]
    bf16* at  = (bf16*)(w + (40ull << 20));        // 8 MB  (total 48 MB)

    cvt_f32_bf16<<<(MROWS * DMODEL / 4 + 255) / 256, 256, 0, stream>>>(x, xb, MROWS * DMODEL / 4);
    cvt_trans<<<dim3(16, 16, 4), 256, 0, stream>>>(wq, wk, wv, wo, wqT, wkT, wvT, woT);
    gemm_qkv<<<dim3(DMODEL / BN, MROWS / BM, 3), 256, 0, stream>>>(xb, wqT, wkT, wvT, Qh, Kh, Vt);
    attn_kernel<<<dim3(1024, 1, 1), 128, 0, stream>>>(Qh, Kh, Vt, at);
    gemm_outp<<<dim3(DMODEL / BN, MROWS / BM), 256, 0, stream>>>(at, woT, out);
}

// Round 8
// 119.059 us; speedup vs baseline: 1.8129x; 1.1034x over previous
//
#include <hip/hip_runtime.h>
#include <hip/hip_bf16.h>

#define NUM_HEADS 16
#define HEAD_DIM 64
#define DMODEL 1024
#define SEQ 2048
#define BATCH 2
#define MROWS (BATCH*SEQ)

typedef __bf16 bf16;
typedef __bf16 bf16x4 __attribute__((ext_vector_type(4)));
typedef __bf16 bf16x8 __attribute__((ext_vector_type(8)));
typedef float f32x4 __attribute__((ext_vector_type(4)));

#define MFMA16(a, b, c) __builtin_amdgcn_mfma_f32_16x16x32_bf16((a), (b), (c), 0, 0, 0)

// 0.125 * log2(e): folded into Q so QK^T logits land in exp2 domain
#define QSCALE 0.1803368801111444f

__device__ __forceinline__ float fast_exp2(float x) {
    float r;
    asm("v_exp_f32 %0, %1" : "=v"(r) : "v"(x));
    return r;
}

__device__ __forceinline__ void gld16(const void* g, void* l) {
    __builtin_amdgcn_global_load_lds(
        (const __attribute__((address_space(1))) void*)g,
        (__attribute__((address_space(3))) void*)l, 16, 0, 0);
}

// ---------------- conversion kernels ----------------

__global__ __launch_bounds__(256) void cvt_f32_bf16(const float* __restrict__ in,
                                                    bf16* __restrict__ out, int n4) {
    int i = blockIdx.x * 256 + threadIdx.x;
    if (i >= n4) return;
    float4 v = *(const float4*)(in + (size_t)i * 4);
    bf16x4 o = { (bf16)v.x, (bf16)v.y, (bf16)v.z, (bf16)v.w };
    *(bf16x4*)(out + (size_t)i * 4) = o;
}

// w [1024][1024] f32 -> wT bf16 [1024][1024], wT[n][k] = w[k][n]
__global__ __launch_bounds__(256) void cvt_trans(const float* __restrict__ w0, const float* __restrict__ w1,
                                                 const float* __restrict__ w2, const float* __restrict__ w3,
                                                 bf16* __restrict__ o0, bf16* __restrict__ o1,
                                                 bf16* __restrict__ o2, bf16* __restrict__ o3) {
    const float* w = blockIdx.z == 0 ? w0 : blockIdx.z == 1 ? w1 : blockIdx.z == 2 ? w2 : w3;
    bf16* o = blockIdx.z == 0 ? o0 : blockIdx.z == 1 ? o1 : blockIdx.z == 2 ? o2 : o3;
    __shared__ bf16 tile[64][65];
    int k0 = blockIdx.y * 64, n0 = blockIdx.x * 64;
    int tc = threadIdx.x & 63;
    int tr0 = threadIdx.x >> 6;
#pragma unroll
    for (int i = 0; i < 16; i++) {
        int r = tr0 + i * 4;  // k row
        tile[r][tc] = (bf16)w[(size_t)(k0 + r) * DMODEL + n0 + tc];
    }
    __syncthreads();
#pragma unroll
    for (int i = 0; i < 16; i++) {
        int r = tr0 + i * 4;  // n row of output
        o[(size_t)(n0 + r) * DMODEL + k0 + tc] = tile[tc][r];
    }
}

// ---------------- GEMM core: C[128][128] tile = A[m][k] * Bt[n][k]^T ----------------

#define BM 128
#define BN 128
#define BK 32

__device__ __forceinline__ void gemm_core(const bf16* __restrict__ A, const bf16* __restrict__ Bt,
                                          int m0, int n0, int Kdim,
                                          bf16* As, bf16* Bs, f32x4 acc[4][4]) {
    int t = threadIdx.x;
    int lane = t & 63;
    int wave = t >> 6;
    int wm = (wave >> 1) * 64;
    int wn = (wave & 1) * 64;
#pragma unroll
    for (int mf = 0; mf < 4; mf++)
#pragma unroll
        for (int nf = 0; nf < 4; nf++) acc[mf][nf] = (f32x4){0.f, 0.f, 0.f, 0.f};

    int arow = lane & 15, kg = lane >> 4;

    for (int k0 = 0; k0 < Kdim; k0 += BK) {
        __syncthreads();
#pragma unroll
        for (int it = 0; it < 2; it++) {
            int chunk = it * 256 + t;
            int rr = chunk >> 2, cc = chunk & 3;
            gld16(A + (size_t)(m0 + rr) * Kdim + k0 + cc * 8, As + chunk * 8);
            gld16(Bt + (size_t)(n0 + rr) * Kdim + k0 + cc * 8, Bs + chunk * 8);
        }
        __syncthreads();
        bf16x8 af[4], bfr[4];
#pragma unroll
        for (int mf = 0; mf < 4; mf++)
            af[mf] = *(const bf16x8*)(As + (wm + mf * 16 + arow) * BK + kg * 8);
#pragma unroll
        for (int nf = 0; nf < 4; nf++)
            bfr[nf] = *(const bf16x8*)(Bs + (wn + nf * 16 + arow) * BK + kg * 8);
#pragma unroll
        for (int mf = 0; mf < 4; mf++)
#pragma unroll
            for (int nf = 0; nf < 4; nf++)
                acc[mf][nf] = MFMA16(af[mf], bfr[nf], acc[mf][nf]);
    }
}

// z=0 -> Q head-major [B][H][S][D], pre-scaled by QSCALE; z=1 -> K head-major; z=2 -> V [B][H][D][S]
__global__ __launch_bounds__(256) void gemm_qkv(const bf16* __restrict__ xb,
                                                const bf16* __restrict__ wqT, const bf16* __restrict__ wkT,
                                                const bf16* __restrict__ wvT,
                                                bf16* __restrict__ Qh, bf16* __restrict__ Kh,
                                                bf16* __restrict__ Vt) {
    __shared__ __attribute__((aligned(16))) bf16 As[BM * BK];
    __shared__ __attribute__((aligned(16))) bf16 Bs[BN * BK];
    int z = blockIdx.z;
    const bf16* Bt = z == 0 ? wqT : z == 1 ? wkT : wvT;
    int m0 = blockIdx.y * BM, n0 = blockIdx.x * BN;
    f32x4 acc[4][4];
    gemm_core(xb, Bt, m0, n0, DMODEL, As, Bs, acc);

    int lane = threadIdx.x & 63, wave = threadIdx.x >> 6;
    int wm = (wave >> 1) * 64, wn = (wave & 1) * 64;
    int col0 = n0 + wn + (lane & 15);
    int row0 = m0 + wm + (lane >> 4) * 4;
    if (z < 2) {
        bf16* O = z == 0 ? Qh : Kh;
        float scl = z == 0 ? QSCALE : 1.0f;
#pragma unroll
        for (int mf = 0; mf < 4; mf++)
#pragma unroll
            for (int nf = 0; nf < 4; nf++) {
                int n = col0 + nf * 16;
                int mb = row0 + mf * 16;
                int hh = n >> 6, d = n & 63;
#pragma unroll
                for (int i2 = 0; i2 < 4; i2++) {
                    int m = mb + i2;
                    int bb = m >> 11, s = m & 2047;
                    O[(((size_t)bb * NUM_HEADS + hh) * SEQ + s) * HEAD_DIM + d] =
                        (bf16)(acc[mf][nf][i2] * scl);
                }
            }
    } else {
#pragma unroll
        for (int mf = 0; mf < 4; mf++)
#pragma unroll
            for (int nf = 0; nf < 4; nf++) {
                int n = col0 + nf * 16;
                int m = row0 + mf * 16;
                int b = m >> 11, s = m & 2047;
                int h = n >> 6, d = n & 63;
                bf16x4 pack = { (bf16)acc[mf][nf][0], (bf16)acc[mf][nf][1],
                                (bf16)acc[mf][nf][2], (bf16)acc[mf][nf][3] };
                *(bf16x4*)(Vt + ((size_t)(b * NUM_HEADS + h) * HEAD_DIM + d) * SEQ + s) = pack;
            }
    }
}

__global__ __launch_bounds__(256) void gemm_outp(const bf16* __restrict__ at,
                                                 const bf16* __restrict__ woT,
                                                 float* __restrict__ out) {
    __shared__ __attribute__((aligned(16))) bf16 As[BM * BK];
    __shared__ __attribute__((aligned(16))) bf16 Bs[BN * BK];
    int m0 = blockIdx.y * BM, n0 = blockIdx.x * BN;
    f32x4 acc[4][4];
    gemm_core(at, woT, m0, n0, DMODEL, As, Bs, acc);

    int lane = threadIdx.x & 63, wave = threadIdx.x >> 6;
    int wm = (wave >> 1) * 64, wn = (wave & 1) * 64;
    int col0 = n0 + wn + (lane & 15);
    int row0 = m0 + wm + (lane >> 4) * 4;
#pragma unroll
    for (int mf = 0; mf < 4; mf++)
#pragma unroll
        for (int nf = 0; nf < 4; nf++) {
            int n = col0 + nf * 16;
            int mb = row0 + mf * 16;
#pragma unroll
            for (int i2 = 0; i2 < 4; i2++)
                out[(size_t)(mb + i2) * DMODEL + n] = acc[mf][nf][i2];
        }
}

// ---------------- flash attention: paired q-tiles, uniform 33-iter chains ----------------
// grid 512, block 256 (4 waves x 16 q-rows = QBLK 64). Each block processes TWO
// q-tiles SEQUENTIALLY: qt = p then qt = 31-p  =>  (p+1)+(32-p) = 33 KV-iters for
// EVERY block. 2 blocks/CU, both resident (40KB LDS), identical length => 8
// waves/CU (2/SIMD) constant to the end — no occupancy decay, no tail (R7's
// killer: 11.8% avg occupancy from chain imbalance with no backfill).
// K/V double-buffered in LDS (global_load_lds 16B, XOR-swizzle via inverse-
// swizzled global source), shared by all 4 waves. XCD map: id&7, 4 (b,h)/XCD.
__global__ __launch_bounds__(256) void attn_kernel(const bf16* __restrict__ Qh, const bf16* __restrict__ Kh,
                                                   const bf16* __restrict__ Vt, bf16* __restrict__ attn) {
    __shared__ __attribute__((aligned(16))) bf16 Kl[2 * 64 * 64];   // 2 x 8KB, swizzled [kv][d]
    __shared__ __attribute__((aligned(16))) bf16 Vl[2 * 64 * 64];   // 2 x 8KB, swizzled [d][kv]
    __shared__ __attribute__((aligned(16))) bf16 Pl[4 * 16 * 64];   // per-wave P, 2KB each
    int id = blockIdx.x;
    int xcd = id & 7, slot = id >> 3;        // slot 0..63
    int bh4 = slot >> 4;                     // 4 (b,h) per XCD
    int pairIdx = slot & 15;                 // q-tile pair p: {p, 31-p}
    int hb = xcd * 4 + bh4;
    int b = hb >> 4, h = hb & 15;
    int t = threadIdx.x, lane = t & 63, wave = t >> 6;
    int l15 = lane & 15, lg = lane >> 4;

    const bf16* Qb = Qh + ((size_t)(b * NUM_HEADS + h) * SEQ) * HEAD_DIM;
    const bf16* Kb = Kh + ((size_t)(b * NUM_HEADS + h) * SEQ) * HEAD_DIM;
    const bf16* Vb = Vt + ((size_t)(b * NUM_HEADS + h) * HEAD_DIM) * SEQ;  // [D][S]

    char* Pw = (char*)Pl + wave * 2048;
    int swz = (l15 & 7) << 4;

    // stage one 64x64 K tile + V tile into LDS buffer bufi, inverse-swizzled source.
    // chunk c (16B): LDS[c*16] holds global linear offset L = c*16 ^ ((c>>3 & 7)<<4)
    // => read side applies  off ^ ((row&7)<<4)  and gets linear data.
    auto STAGE = [&](int bufi, int kv0n) {
#pragma unroll
        for (int j = 0; j < 2; j++) {
            int c = j * 256 + t;                         // 0..511
            int L = (c * 16) ^ (((c >> 3) & 7) << 4);
            int row = c >> 3, cole = (L & 127) >> 1;     // row 0..63, element col 0..63
            gld16(Kb + (size_t)(kv0n + row) * HEAD_DIM + cole,
                  (char*)Kl + (size_t)bufi * 8192 + c * 16);
            gld16(Vb + (size_t)row * SEQ + kv0n + cole,
                  (char*)Vl + (size_t)bufi * 8192 + c * 16);
        }
    };

#pragma unroll 1
    for (int seg = 0; seg < 2; seg++) {
        int qt = seg ? (31 - pairIdx) : pairIdx;  // q-tile of 64 rows
        int q0w = qt * 64 + wave * 16;            // this wave's 16 q-rows
        int nkt = qt + 1;                         // KV tiles of 64

        // Q fragment (pre-scaled by QSCALE in GEMM epilogue)
        bf16x8 qf[2];
#pragma unroll
        for (int ks = 0; ks < 2; ks++)
            qf[ks] = *(const bf16x8*)(Qb + (size_t)(q0w + l15) * HEAD_DIM + ks * 32 + lg * 8);

        f32x4 oacc[4];
#pragma unroll
        for (int df = 0; df < 4; df++) oacc[df] = (f32x4){0.f, 0.f, 0.f, 0.f};
        float mrun = -1e30f, lrun = 0.f;

        STAGE(0, 0);
        __syncthreads();
        int buf = 0;

        for (int kt = 0; kt < nkt; kt++) {
            int kv0 = kt * 64;
            if (kt + 1 < nkt) STAGE(buf ^ 1, kv0 + 64);   // async prefetch under compute

            const char* KL = (const char*)Kl + (size_t)buf * 8192;
            const char* VL = (const char*)Vl + (size_t)buf * 8192;
            // QK^T (swapped): st[cf][i] = S[q=q0w+l15][kv = kv0+cf*16+lg*4+i]
            f32x4 st[4];
            __builtin_amdgcn_s_setprio(1);
#pragma unroll
            for (int cf = 0; cf < 4; cf++) {
                bf16x8 kfr[2];
#pragma unroll
                for (int ks = 0; ks < 2; ks++) {
                    int off = ((cf * 16 + l15) * 128 + ks * 64 + lg * 16) ^ swz;
                    kfr[ks] = *(const bf16x8*)(KL + off);
                }
                st[cf] = (f32x4){0.f, 0.f, 0.f, 0.f};
#pragma unroll
                for (int ks = 0; ks < 2; ks++)
                    st[cf] = MFMA16(kfr[ks], qf[ks], st[cf]);
            }
            __builtin_amdgcn_s_setprio(0);
            // causal mask: only the last tile overlaps the diagonal
            if (kt == nkt - 1) {
                int qrow = q0w + l15;
#pragma unroll
                for (int cf = 0; cf < 4; cf++)
#pragma unroll
                    for (int i = 0; i < 4; i++) {
                        int kv = kv0 + cf * 16 + lg * 4 + i;
                        if (kv > qrow) st[cf][i] = -1e30f;
                    }
            }
            // softmax (tree reductions; defer-max T13)
            float m01 = fmaxf(fmaxf(st[0][0], st[0][1]), fmaxf(st[0][2], st[0][3]));
            float m23 = fmaxf(fmaxf(st[1][0], st[1][1]), fmaxf(st[1][2], st[1][3]));
            float m45 = fmaxf(fmaxf(st[2][0], st[2][1]), fmaxf(st[2][2], st[2][3]));
            float m67 = fmaxf(fmaxf(st[3][0], st[3][1]), fmaxf(st[3][2], st[3][3]));
            float mx = fmaxf(fmaxf(m01, m23), fmaxf(m45, m67));
            mx = fmaxf(mx, __shfl_xor(mx, 16, 64));
            mx = fmaxf(mx, __shfl_xor(mx, 32, 64));
            if (!__all(mx <= mrun + 8.0f)) {
                float mnew = fmaxf(mrun, mx);
                float alpha = fast_exp2(mrun - mnew);
                float av[4];
#pragma unroll
                for (int i = 0; i < 4; i++) av[i] = __shfl(alpha, lg * 4 + i, 64);
#pragma unroll
                for (int df = 0; df < 4; df++)
#pragma unroll
                    for (int i = 0; i < 4; i++) oacc[df][i] *= av[i];
                lrun *= alpha;
                mrun = mnew;
            }
            float psc[4];
            bf16x4 pb[4];
#pragma unroll
            for (int cf = 0; cf < 4; cf++) {
                float p0 = fast_exp2(st[cf][0] - mrun);
                float p1 = fast_exp2(st[cf][1] - mrun);
                float p2 = fast_exp2(st[cf][2] - mrun);
                float p3 = fast_exp2(st[cf][3] - mrun);
                psc[cf] = (p0 + p1) + (p2 + p3);
                pb[cf][0] = (bf16)p0; pb[cf][1] = (bf16)p1;
                pb[cf][2] = (bf16)p2; pb[cf][3] = (bf16)p3;
            }
            float ps = (psc[0] + psc[1]) + (psc[2] + psc[3]);
            ps += __shfl_xor(ps, 16, 64);
            ps += __shfl_xor(ps, 32, 64);
            lrun += ps;
            // P -> per-wave LDS (XOR-swizzled rows)
#pragma unroll
            for (int cf = 0; cf < 4; cf++) {
                int off = (l15 * 128 + cf * 32 + lg * 8) ^ swz;
                *(bf16x4*)(Pw + off) = pb[cf];
            }
            // read P back as PV A-fragments
            bf16x8 pa[2];
#pragma unroll
            for (int ks = 0; ks < 2; ks++) {
                int off = (l15 * 128 + ks * 64 + lg * 16) ^ swz;
                pa[ks] = *(const bf16x8*)(Pw + off);
            }
            // PV: V from LDS (swizzled [d][kv])
            __builtin_amdgcn_s_setprio(1);
#pragma unroll
            for (int ks = 0; ks < 2; ks++)
#pragma unroll
                for (int df = 0; df < 4; df++) {
                    int off = ((df * 16 + l15) * 128 + ks * 64 + lg * 16) ^ swz;
                    bf16x8 bv = *(const bf16x8*)(VL + off);
                    oacc[df] = MFMA16(pa[ks], bv, oacc[df]);
                }
            __builtin_amdgcn_s_setprio(0);

            __syncthreads();   // stage(kt+1) complete; safe to flip buffers
            buf ^= 1;
        }

        // epilogue: divide row q by lrun; stats live at lane q (q<16)
        float lrec = 1.0f / lrun;
        float lv[4];
#pragma unroll
        for (int i = 0; i < 4; i++) lv[i] = __shfl(lrec, lg * 4 + i, 64);
#pragma unroll
        for (int df = 0; df < 4; df++)
#pragma unroll
            for (int i = 0; i < 4; i++) {
                int qrow = q0w + lg * 4 + i;
                int d = df * 16 + l15;
                attn[((size_t)(b * SEQ + qrow)) * DMODEL + h * HEAD_DIM + d] = (bf16)(oacc[df][i] * lv[i]);
            }
        // all LDS reads of this segment completed before its last __syncthreads;
        // next segment's STAGE(0,0) is ordered behind that barrier for all waves.
    }
}

// ---------------- launch ----------------

extern "C" void kernel_launch(void* const* d_in, const int* in_sizes, int n_in,
                              void* d_out, int out_size, void* d_ws, size_t ws_size,
                              hipStream_t stream) {
    const float* x  = (const float*)d_in[0];
    const float* wq = (const float*)d_in[1];
    const float* wk = (const float*)d_in[2];
    const float* wv = (const float*)d_in[3];
    const float* wo = (const float*)d_in[4];
    float* out = (float*)d_out;

    char* w = (char*)d_ws;
    bf16* xb  = (bf16*)(w);                        // 8 MB
    bf16* wqT = (bf16*)(w + (8ull  << 20));        // 2 MB
    bf16* wkT = (bf16*)(w + (10ull << 20));
    bf16* wvT = (bf16*)(w + (12ull << 20));
    bf16* woT = (bf16*)(w + (14ull << 20));
    bf16* Qh  = (bf16*)(w + (16ull << 20));        // 8 MB, [B][H][S][D]
    bf16* Kh  = (bf16*)(w + (24ull << 20));        // 8 MB, [B][H][S][D]
    bf16* Vt  = (bf16*)(w + (32ull << 20));        // 8 MB, [B][H][D][S]
    bf16* at  = (bf16*)(w + (40ull << 20));        // 8 MB  (total 48 MB)

    cvt_f32_bf16<<<(MROWS * DMODEL / 4 + 255) / 256, 256, 0, stream>>>(x, xb, MROWS * DMODEL / 4);
    cvt_trans<<<dim3(16, 16, 4), 256, 0, stream>>>(wq, wk, wv, wo, wqT, wkT, wvT, woT);
    gemm_qkv<<<dim3(DMODEL / BN, MROWS / BM, 3), 256, 0, stream>>>(xb, wqT, wkT, wvT, Qh, Kh, Vt);
    attn_kernel<<<dim3(512, 1, 1), 256, 0, stream>>>(Qh, Kh, Vt, at);
    gemm_outp<<<dim3(DMODEL / BN, MROWS / BM), 256, 0, stream>>>(at, woT, out);
}